// Round 1
// baseline (17029.713 us; speedup 1.0000x reference)
//
#include <hip/hip_runtime.h>

// ---------------------------------------------------------------------------
// Tube_fps model forward, fp32. Layouts:
//   seq : (8, 1034, 768) rows 0..833 = transformer stream, 834..1033 = spa
//   z   : (8, 834, 768) residual stream
//   fmid: (8, 3072, 834)
// ---------------------------------------------------------------------------

// ---------------- weight trilinear resize (jax.image.resize, antialias) ----
__device__ __forceinline__ void dim_weights(int j, int O, float* w) {
  float inv = 8.0f / (float)O;
  float ks  = inv > 1.0f ? inv : 1.0f;   // antialias widen on downsample
  float sf  = ((float)j + 0.5f) * inv - 0.5f;
  float tot = 0.f;
#pragma unroll
  for (int i = 0; i < 8; i++) {
    float xx = fabsf(sf - (float)i) / ks;
    float t  = fmaxf(0.f, 1.f - xx);
    w[i] = t; tot += t;
  }
  float r = 1.f / tot;
#pragma unroll
  for (int i = 0; i < 8; i++) w[i] *= r;
}

__global__ void resize_w_kernel(const float* __restrict__ src, float* __restrict__ dst,
                                int OD, int OH, int OW) {
  int idx = blockIdx.x * 256 + threadIdx.x;
  int tot = 2304 * OD * OH * OW;
  if (idx >= tot) return;
  int ow = idx % OW; int t = idx / OW;
  int oh = t % OH;   t /= OH;
  int od = t % OD;   int oc = t / OD;
  float wd[8], wh[8], ww[8];
  dim_weights(od, OD, wd);
  dim_weights(oh, OH, wh);
  dim_weights(ow, OW, ww);
  const float* s = src + (size_t)oc * 512;
  float acc = 0.f;
  for (int d = 0; d < 8; d++) {
    if (wd[d] == 0.f) continue;
    for (int h = 0; h < 8; h++) {
      if (wh[h] == 0.f) continue;
      float w2 = wd[d] * wh[h];
      for (int w = 0; w < 8; w++) {
        float w3 = w2 * ww[w];
        if (w3 != 0.f) acc += w3 * s[d * 64 + h * 8 + w];
      }
    }
  }
  dst[idx] = acc;
}

// ---------------- im2col for tubelet conv3d --------------------------------
__global__ void im2col_kernel(const float* __restrict__ x, float* __restrict__ col,
                              int P, int K, int L,
                              int KD, int KH, int KW, int SD, int SH, int SW) {
  int idx = blockIdx.x * 256 + threadIdx.x;
  if (idx >= P * K) return;
  int p = idx / K;  int k = idx - p * K;
  int n = p / L;    int lp = p - n * L;
  int ld = lp / 49; int r = lp - ld * 49;
  int lh = r / 7;   int lw = r - lh * 7;
  int kvol = KD * KH * KW;
  int c = k / kvol; int r2 = k - c * kvol;
  int khw = KH * KW;
  int kd = r2 / khw; int r3 = r2 - kd * khw;
  int kh = r3 / KW;  int kw = r3 - kh * KW;
  int zd = ld * SD + kd, zh = lh * SH + kh, zw = lw * SW + kw;
  col[(size_t)p * K + k] =
      x[((((size_t)n * 3 + c) * 64 + zd) * 224 + zh) * 224 + zw];
}

// ---------------- generic fp32 GEMM: C[i][j] = sum_k A[i][k]*B[j][k] -------
// map_mode 0: out[i*out_ld + j]; map_mode 1: seq scatter (n=i/map_L)
__global__ __launch_bounds__(256) void gemm_nt(
    const float* __restrict__ A, int lda,
    const float* __restrict__ B, int ldb,
    int I, int J, int K,
    const float* __restrict__ bias,
    const float* __restrict__ res,
    float* __restrict__ out,
    int map_mode, int map_L, int map_off, int out_ld) {
  __shared__ float As[16 * 136];
  __shared__ float Bs[16 * 136];
  const int tid = threadIdx.x;
  const int i0 = blockIdx.y * 128;
  const int j0 = blockIdx.x * 128;
  const int lr = tid >> 2;
  const int lk = (tid & 3) << 2;
  const int tx = tid & 15;
  const int ty = tid >> 4;
  float acc[8][8];
#pragma unroll
  for (int u = 0; u < 8; u++)
#pragma unroll
    for (int v = 0; v < 8; v++) acc[u][v] = 0.f;

  for (int k0 = 0; k0 < K; k0 += 16) {
    float4 a0 = make_float4(0, 0, 0, 0), a1 = a0, b0 = a0, b1 = a0;
    int ra = i0 + lr;
    if (ra < I)      a0 = *(const float4*)(A + (size_t)ra * lda + (k0 + lk));
    if (ra + 64 < I) a1 = *(const float4*)(A + (size_t)(ra + 64) * lda + (k0 + lk));
    int rb = j0 + lr;
    if (rb < J)      b0 = *(const float4*)(B + (size_t)rb * ldb + (k0 + lk));
    if (rb + 64 < J) b1 = *(const float4*)(B + (size_t)(rb + 64) * ldb + (k0 + lk));
    __syncthreads();
    As[(lk + 0) * 136 + lr] = a0.x; As[(lk + 1) * 136 + lr] = a0.y;
    As[(lk + 2) * 136 + lr] = a0.z; As[(lk + 3) * 136 + lr] = a0.w;
    As[(lk + 0) * 136 + lr + 64] = a1.x; As[(lk + 1) * 136 + lr + 64] = a1.y;
    As[(lk + 2) * 136 + lr + 64] = a1.z; As[(lk + 3) * 136 + lr + 64] = a1.w;
    Bs[(lk + 0) * 136 + lr] = b0.x; Bs[(lk + 1) * 136 + lr] = b0.y;
    Bs[(lk + 2) * 136 + lr] = b0.z; Bs[(lk + 3) * 136 + lr] = b0.w;
    Bs[(lk + 0) * 136 + lr + 64] = b1.x; Bs[(lk + 1) * 136 + lr + 64] = b1.y;
    Bs[(lk + 2) * 136 + lr + 64] = b1.z; Bs[(lk + 3) * 136 + lr + 64] = b1.w;
    __syncthreads();
#pragma unroll
    for (int kk = 0; kk < 16; kk++) {
      float4 aA = *(const float4*)&As[kk * 136 + ty * 4];
      float4 aB = *(const float4*)&As[kk * 136 + 64 + ty * 4];
      float4 bA = *(const float4*)&Bs[kk * 136 + tx * 4];
      float4 bB = *(const float4*)&Bs[kk * 136 + 64 + tx * 4];
      float av[8] = {aA.x, aA.y, aA.z, aA.w, aB.x, aB.y, aB.z, aB.w};
      float bv[8] = {bA.x, bA.y, bA.z, bA.w, bB.x, bB.y, bB.z, bB.w};
#pragma unroll
      for (int u = 0; u < 8; u++)
#pragma unroll
        for (int v = 0; v < 8; v++)
          acc[u][v] = fmaf(av[u], bv[v], acc[u][v]);
    }
  }

#pragma unroll
  for (int u = 0; u < 8; u++) {
    int i = i0 + ty * 4 + (u & 3) + ((u >> 2) << 6);
    if (i >= I) continue;
    size_t rowbase;
    if (map_mode == 0) {
      rowbase = (size_t)i * out_ld;
    } else {
      int nn = i / map_L; int ll = i - nn * map_L;
      rowbase = ((size_t)(nn * 1034 + map_off + ll)) * 768;
    }
#pragma unroll
    for (int v = 0; v < 8; v++) {
      int j = j0 + tx * 4 + (v & 3) + ((v >> 2) << 6);
      if (j >= J) continue;
      float val = acc[u][v];
      if (bias) val += bias[j];
      size_t oi = rowbase + j;
      if (res) val += res[oi];
      out[oi] = val;
    }
  }
}

// ---------------- conv1d (k=9, pad 4) as GEMM over virtual im2col ----------
// C[p][o] = sum_{c,dt} IN[n][c][t+dt-4] * W[o][c*9+dt]
// mode 1: out (n,3072,834) with exact GELU (LDS-transposed store)
// mode 2: out[p*768+o] = acc + bias[o] + res[...]
__global__ __launch_bounds__(256) void gemm_conv1d(
    const float* __restrict__ W, const float* __restrict__ IN, int Cin,
    int I, int J, int K,
    const float* __restrict__ bias, const float* __restrict__ res,
    float* __restrict__ out, int mode) {
  __shared__ float smem[2 * 16 * 136];
  float* Ps  = smem;             // positions tile [16][136]
  float* Wsm = smem + 16 * 136;  // weights tile   [16][136]
  const int tid = threadIdx.x;
  const int j0 = blockIdx.x * 128;
  const int p0 = blockIdx.y * 128;
  const int lr = tid >> 2;
  const int lk = (tid & 3) << 2;
  const int iw = tid & 31;
  const int kv = tid >> 5;
  const int tx = tid & 15;
  const int ty = tid >> 4;
  float acc[8][8];
#pragma unroll
  for (int u = 0; u < 8; u++)
#pragma unroll
    for (int v = 0; v < 8; v++) acc[u][v] = 0.f;

  for (int k0 = 0; k0 < K; k0 += 16) {
    float4 w0 = make_float4(0, 0, 0, 0), w1 = w0;
    if (j0 + lr < J)      w0 = *(const float4*)(W + (size_t)(j0 + lr) * K + k0 + lk);
    if (j0 + lr + 64 < J) w1 = *(const float4*)(W + (size_t)(j0 + lr + 64) * K + k0 + lk);
    float bvals[8];
#pragma unroll
    for (int kq = 0; kq < 2; kq++) {
      int kk = kv + kq * 8;
      int k = k0 + kk;
      int c = k / 9;
      int dt = k - c * 9;
#pragma unroll
      for (int uu = 0; uu < 4; uu++) {
        int p = p0 + iw * 4 + uu;
        float vv = 0.f;
        if (p < I) {
          int nn = p / 834;
          int t = p - nn * 834;
          int tin = t + dt - 4;
          if (tin >= 0 && tin < 834)
            vv = IN[((size_t)nn * Cin + c) * 834 + tin];
        }
        bvals[kq * 4 + uu] = vv;
      }
    }
    __syncthreads();
    Wsm[(lk + 0) * 136 + lr] = w0.x; Wsm[(lk + 1) * 136 + lr] = w0.y;
    Wsm[(lk + 2) * 136 + lr] = w0.z; Wsm[(lk + 3) * 136 + lr] = w0.w;
    Wsm[(lk + 0) * 136 + lr + 64] = w1.x; Wsm[(lk + 1) * 136 + lr + 64] = w1.y;
    Wsm[(lk + 2) * 136 + lr + 64] = w1.z; Wsm[(lk + 3) * 136 + lr + 64] = w1.w;
#pragma unroll
    for (int kq = 0; kq < 2; kq++)
#pragma unroll
      for (int uu = 0; uu < 4; uu++)
        Ps[(kv + kq * 8) * 136 + iw * 4 + uu] = bvals[kq * 4 + uu];
    __syncthreads();
#pragma unroll
    for (int kk = 0; kk < 16; kk++) {
      float4 aA = *(const float4*)&Ps[kk * 136 + ty * 4];
      float4 aB = *(const float4*)&Ps[kk * 136 + 64 + ty * 4];
      float4 bA = *(const float4*)&Wsm[kk * 136 + tx * 4];
      float4 bB = *(const float4*)&Wsm[kk * 136 + 64 + tx * 4];
      float av[8] = {aA.x, aA.y, aA.z, aA.w, aB.x, aB.y, aB.z, aB.w};
      float bv[8] = {bA.x, bA.y, bA.z, bA.w, bB.x, bB.y, bB.z, bB.w};
#pragma unroll
      for (int u = 0; u < 8; u++)
#pragma unroll
        for (int v = 0; v < 8; v++)
          acc[u][v] = fmaf(av[u], bv[v], acc[u][v]);
    }
  }

  if (mode == 2) {
#pragma unroll
    for (int u = 0; u < 8; u++) {
      int p = p0 + ty * 4 + (u & 3) + ((u >> 2) << 6);
      if (p >= I) continue;
#pragma unroll
      for (int v = 0; v < 8; v++) {
        int o = j0 + tx * 4 + (v & 3) + ((v >> 2) << 6);
        if (o >= J) continue;
        size_t oi = (size_t)p * 768 + o;
        out[oi] = acc[u][v] + bias[o] + res[oi];
      }
    }
  } else {
    // transpose 32-o chunks through LDS, GELU, store (n,3072,834) coalesced
    for (int cc = 0; cc < 4; cc++) {
      __syncthreads();
#pragma unroll
      for (int v = 0; v < 8; v++) {
        int o_local = tx * 4 + (v & 3) + ((v >> 2) << 6);
        if ((o_local >> 5) == cc) {
#pragma unroll
          for (int u = 0; u < 8; u++) {
            int p_local = ty * 4 + (u & 3) + ((u >> 2) << 6);
            smem[(o_local & 31) * 132 + p_local] = acc[u][v];
          }
        }
      }
      __syncthreads();
      int rr = tid >> 3, sg = tid & 7;
      int o = j0 + cc * 32 + rr;
      if (o < J) {
        float bo = bias[o];
        for (int wq = 0; wq < 16; wq++) {
          int p = p0 + sg * 16 + wq;
          if (p < I) {
            int nn = p / 834;
            int t = p - nn * 834;
            float val = smem[rr * 132 + sg * 16 + wq] + bo;
            val = 0.5f * val * (1.f + erff(val * 0.70710678118654752f));
            out[((size_t)nn * 3072 + o) * 834 + t] = val;
          }
        }
      }
    }
  }
}

// ---------------- cls/pos add ----------------------------------------------
__global__ void addpos_kernel(float* __restrict__ seq, const float* __restrict__ pos,
                              const float* __restrict__ cls) {
  int idx = blockIdx.x * 256 + threadIdx.x;
  if (idx >= 8 * 834 * 768) return;
  int c = idx % 768;
  int t = (idx / 768) % 834;
  int n = idx / (768 * 834);
  size_t off = ((size_t)(n * 1034 + t)) * 768 + c;
  float v = (t == 0) ? cls[c] : seq[off];
  seq[off] = v + pos[(size_t)t * 768 + c];
}

// ---------------- GroupNorm (32 groups, eps 1e-6) over seq rows 0..833 -----
__global__ __launch_bounds__(256) void groupnorm_kernel(
    const float* __restrict__ seq, const float* __restrict__ g,
    const float* __restrict__ b, float* __restrict__ out) {
  int blk = blockIdx.x;
  int n = blk >> 5, grp = blk & 31;
  int tid = threadIdx.x;
  float s = 0.f, sq = 0.f;
  for (int e = tid; e < 20016; e += 256) {
    int t = e / 24; int cc = e - t * 24;
    float v = seq[((size_t)(n * 1034 + t)) * 768 + grp * 24 + cc];
    s += v; sq += v * v;
  }
  __shared__ float red[8];
#pragma unroll
  for (int off = 32; off >= 1; off >>= 1) {
    s += __shfl_down(s, off, 64); sq += __shfl_down(sq, off, 64);
  }
  if ((tid & 63) == 0) { red[tid >> 6] = s; red[4 + (tid >> 6)] = sq; }
  __syncthreads();
  s = red[0] + red[1] + red[2] + red[3];
  sq = red[4] + red[5] + red[6] + red[7];
  float m = s * (1.f / 20016.f);
  float var = sq * (1.f / 20016.f) - m * m;
  float rs = rsqrtf(var + 1e-6f);
  for (int e = tid; e < 20016; e += 256) {
    int t = e / 24; int cc = e - t * 24;
    int c = grp * 24 + cc;
    float v = seq[((size_t)(n * 1034 + t)) * 768 + c];
    out[((size_t)(n * 834 + t)) * 768 + c] = (v - m) * rs * g[c] + b[c];
  }
}

// ---------------- LayerNorm per row of 768 ---------------------------------
__global__ __launch_bounds__(256) void ln_rows_kernel(
    const float* __restrict__ in, const float* __restrict__ g,
    const float* __restrict__ b, float* __restrict__ out, float eps) {
  int row = blockIdx.x, tid = threadIdx.x;
  const float* xp = in + (size_t)row * 768;
  float v0 = xp[tid], v1 = xp[tid + 256], v2 = xp[tid + 512];
  float s = v0 + v1 + v2;
  float sq = v0 * v0 + v1 * v1 + v2 * v2;
  __shared__ float red[8];
#pragma unroll
  for (int off = 32; off >= 1; off >>= 1) {
    s += __shfl_down(s, off, 64); sq += __shfl_down(sq, off, 64);
  }
  if ((tid & 63) == 0) { red[tid >> 6] = s; red[4 + (tid >> 6)] = sq; }
  __syncthreads();
  s = red[0] + red[1] + red[2] + red[3];
  sq = red[4] + red[5] + red[6] + red[7];
  float m = s * (1.f / 768.f);
  float var = sq * (1.f / 768.f) - m * m;
  float rs = rsqrtf(var + eps);
  float* op = out + (size_t)row * 768;
  op[tid]       = (v0 - m) * rs * g[tid]       + b[tid];
  op[tid + 256] = (v1 - m) * rs * g[tid + 256] + b[tid + 256];
  op[tid + 512] = (v2 - m) * rs * g[tid + 512] + b[tid + 512];
}

// ---------------- (n,t,c) -> (n,c,t) transpose -----------------------------
__global__ __launch_bounds__(256) void transpose_tc_kernel(
    const float* __restrict__ in, float* __restrict__ out) {
  __shared__ float tile[32][33];
  int n = blockIdx.z;
  int c0 = blockIdx.y * 32, t0 = blockIdx.x * 32;
  int lx = threadIdx.x & 31, ly0 = threadIdx.x >> 5;
#pragma unroll
  for (int it = 0; it < 4; it++) {
    int ly = ly0 + it * 8;
    int t = t0 + ly;
    tile[ly][lx] = (t < 834) ? in[((size_t)(n * 834 + t)) * 768 + c0 + lx] : 0.f;
  }
  __syncthreads();
#pragma unroll
  for (int it = 0; it < 4; it++) {
    int cy = ly0 + it * 8;
    int t = t0 + lx;
    if (t < 834)
      out[((size_t)(n * 768) + c0 + cy) * 834 + t] = tile[lx][cy];
  }
}

// ---------------- flash attention (fp32, online softmax) -------------------
// block: 16 q-rows x 16 col-groups; BK=64; head dim 48
__global__ __launch_bounds__(256) void attn_kernel(
    const float* __restrict__ Q, const float* __restrict__ K,
    const float* __restrict__ V, float* __restrict__ O) {
  const int S = 834;
  __shared__ float Qs[16][49];
  __shared__ float Ks[64][49];
  __shared__ float Vs[64][49];
  __shared__ float Ps[16][64];
  const int tid = threadIdx.x;
  const int r = tid >> 4;
  const int cg = tid & 15;
  const int qb = blockIdx.x, head = blockIdx.y, n = blockIdx.z;
  const int qi = qb * 16 + r;
  const size_t base = ((size_t)n * S) * 768 + head * 48;
#pragma unroll
  for (int u = 0; u < 3; u++) {
    int d = cg * 3 + u;
    Qs[r][d] = (qi < S) ? Q[base + (size_t)qi * 768 + d] : 0.f;
  }
  float m_i = -1e30f, l_i = 0.f;
  float av0 = 0.f, av1 = 0.f, av2 = 0.f;
  __syncthreads();
  for (int kt = 0; kt < S; kt += 64) {
    int kn = S - kt; if (kn > 64) kn = 64;
    for (int e = tid; e < 64 * 48; e += 256) {
      int kk = e / 48, d = e - kk * 48;
      int ki = kt + kk;
      float kv = 0.f, vv = 0.f;
      if (ki < S) {
        kv = K[base + (size_t)ki * 768 + d];
        vv = V[base + (size_t)ki * 768 + d];
      }
      Ks[kk][d] = kv; Vs[kk][d] = vv;
    }
    __syncthreads();
    float s0 = 0, s1 = 0, s2 = 0, s3 = 0;
#pragma unroll 8
    for (int d = 0; d < 48; d++) {
      float qd = Qs[r][d];
      s0 = fmaf(qd, Ks[cg][d], s0);
      s1 = fmaf(qd, Ks[cg + 16][d], s1);
      s2 = fmaf(qd, Ks[cg + 32][d], s2);
      s3 = fmaf(qd, Ks[cg + 48][d], s3);
    }
    const float sc = 0.14433756729740644f;  // 48^-0.5
    s0 = (cg      < kn) ? s0 * sc : -1e30f;
    s1 = (cg + 16 < kn) ? s1 * sc : -1e30f;
    s2 = (cg + 32 < kn) ? s2 * sc : -1e30f;
    s3 = (cg + 48 < kn) ? s3 * sc : -1e30f;
    float mloc = fmaxf(fmaxf(s0, s1), fmaxf(s2, s3));
#pragma unroll
    for (int off = 8; off >= 1; off >>= 1)
      mloc = fmaxf(mloc, __shfl_xor(mloc, off, 16));
    float mnew = fmaxf(m_i, mloc);
    float p0 = expf(s0 - mnew), p1 = expf(s1 - mnew);
    float p2 = expf(s2 - mnew), p3 = expf(s3 - mnew);
    float ps = p0 + p1 + p2 + p3;
#pragma unroll
    for (int off = 8; off >= 1; off >>= 1) ps += __shfl_xor(ps, off, 16);
    float alpha = expf(m_i - mnew);
    l_i = l_i * alpha + ps;
    av0 *= alpha; av1 *= alpha; av2 *= alpha;
    Ps[r][cg] = p0; Ps[r][cg + 16] = p1; Ps[r][cg + 32] = p2; Ps[r][cg + 48] = p3;
    m_i = mnew;
    int d0 = cg * 3;
#pragma unroll 4
    for (int k4 = 0; k4 < 16; k4++) {
      float4 pv = *(const float4*)&Ps[r][k4 * 4];
      av0 = fmaf(pv.x, Vs[k4 * 4 + 0][d0 + 0], av0);
      av1 = fmaf(pv.x, Vs[k4 * 4 + 0][d0 + 1], av1);
      av2 = fmaf(pv.x, Vs[k4 * 4 + 0][d0 + 2], av2);
      av0 = fmaf(pv.y, Vs[k4 * 4 + 1][d0 + 0], av0);
      av1 = fmaf(pv.y, Vs[k4 * 4 + 1][d0 + 1], av1);
      av2 = fmaf(pv.y, Vs[k4 * 4 + 1][d0 + 2], av2);
      av0 = fmaf(pv.z, Vs[k4 * 4 + 2][d0 + 0], av0);
      av1 = fmaf(pv.z, Vs[k4 * 4 + 2][d0 + 1], av1);
      av2 = fmaf(pv.z, Vs[k4 * 4 + 2][d0 + 2], av2);
      av0 = fmaf(pv.w, Vs[k4 * 4 + 3][d0 + 0], av0);
      av1 = fmaf(pv.w, Vs[k4 * 4 + 3][d0 + 1], av1);
      av2 = fmaf(pv.w, Vs[k4 * 4 + 3][d0 + 2], av2);
    }
    __syncthreads();
  }
  if (qi < S) {
    float inv = 1.f / l_i;
    O[base + (size_t)qi * 768 + cg * 3 + 0] = av0 * inv;
    O[base + (size_t)qi * 768 + cg * 3 + 1] = av1 * inv;
    O[base + (size_t)qi * 768 + cg * 3 + 2] = av2 * inv;
  }
}

// ---------------- GRU (torch cell) + masked-mean head, 1 wave / sample -----
__global__ __launch_bounds__(64) void gru_kernel(
    const float* __restrict__ gx, const float* __restrict__ whh,
    const float* __restrict__ bhh, const float* __restrict__ qh_w,
    const float* __restrict__ qh_b, const int* __restrict__ fea_len,
    float* __restrict__ out) {
  int n = blockIdx.x;
  int lane = threadIdx.x;
  bool lo = lane < 32;
  float w1[32], w2[32];
#pragma unroll
  for (int i = 0; i < 32; i++) w1[i] = whh[lane * 32 + i];
#pragma unroll
  for (int i = 0; i < 32; i++) w2[i] = lo ? whh[(64 + lane) * 32 + i] : 0.f;
  float bh1 = bhh[lane];
  float bh2 = lo ? bhh[64 + lane] : 0.f;
  float qw  = lo ? qh_w[lane] : 0.f;
  float h_all[32];
#pragma unroll
  for (int i = 0; i < 32; i++) h_all[i] = 0.f;
  float hown = 0.f, acc = 0.f;
  int L = fea_len[n] + 834;
  const float* gb = gx + (size_t)n * 1034 * 96;
  for (int t = 0; t < 1034; t++) {
    if (t >= L) break;  // steps >= L don't affect masked output
    const float* g = gb + (size_t)t * 96;
    float g1 = g[lane];
    float g2 = lo ? g[64 + lane] : 0.f;
    float gh1 = bh1, gh2 = bh2;
#pragma unroll
    for (int i = 0; i < 32; i++) {
      gh1 = fmaf(h_all[i], w1[i], gh1);
      gh2 = fmaf(h_all[i], w2[i], gh2);
    }
    float s1 = g1 + gh1;                 // lane<32: r-gate; lane 32..63: z-gate
    float szg = __shfl(s1, (lane + 32) & 63, 64);
    float rg = 1.f / (1.f + expf(-s1));
    float zg = 1.f / (1.f + expf(-szg));
    float nn = tanhf(fmaf(rg, gh2, g2));
    float hn = (1.f - zg) * nn + zg * hown;
    if (lo) { hown = hn; acc = fmaf(hn, qw, acc); }
#pragma unroll
    for (int i = 0; i < 32; i++) h_all[i] = __shfl(hn, i, 64);
  }
#pragma unroll
  for (int off = 16; off >= 1; off >>= 1) acc += __shfl_down(acc, off, 64);
  if (lane == 0) out[n] = acc / (float)L + qh_b[0];
}

// ---------------------------------------------------------------------------
extern "C" void kernel_launch(void* const* d_in, const int* in_sizes, int n_in,
                              void* d_out, int out_size, void* d_ws, size_t ws_size,
                              hipStream_t stream) {
  const float* x        = (const float*)d_in[0];
  const float* spa_feas = (const float*)d_in[1];
  const int*   fea_len  = (const int*)d_in[2];
  const float* pos_emb  = (const float*)d_in[3];
  const float* cls_tok  = (const float*)d_in[4];
  const float* conv_w   = (const float*)d_in[5];
  const float* conv_b   = (const float*)d_in[6];
  const float* gn_g     = (const float*)d_in[7];
  const float* gn_b     = (const float*)d_in[8];
  const float* pin_w    = (const float*)d_in[9];
  const float* pin_b    = (const float*)d_in[10];
  const float* ln_g[3]  = {(const float*)d_in[11], (const float*)d_in[13], (const float*)d_in[15]};
  const float* ln_b[3]  = {(const float*)d_in[12], (const float*)d_in[14], (const float*)d_in[16]};
  const float* wq[2] = {(const float*)d_in[17], (const float*)d_in[22]};
  const float* wk[2] = {(const float*)d_in[18], (const float*)d_in[23]};
  const float* wv[2] = {(const float*)d_in[19], (const float*)d_in[24]};
  const float* wo[2] = {(const float*)d_in[20], (const float*)d_in[25]};
  const float* bo[2] = {(const float*)d_in[21], (const float*)d_in[26]};
  const float* ff_w1 = (const float*)d_in[27];
  const float* ff_b1 = (const float*)d_in[28];
  const float* ff_w2 = (const float*)d_in[29];
  const float* ff_b2 = (const float*)d_in[30];
  const float* pout_w = (const float*)d_in[31];
  const float* pout_b = (const float*)d_in[32];
  const float* spa_w  = (const float*)d_in[33];
  const float* spa_b  = (const float*)d_in[34];
  const float* gru_wih = (const float*)d_in[35];
  const float* gru_whh = (const float*)d_in[36];
  const float* gru_bih = (const float*)d_in[37];
  const float* gru_bhh = (const float*)d_in[38];
  const float* qh_w = (const float*)d_in[39];
  const float* qh_b = (const float*)d_in[40];
  float* outp = (float*)d_out;

  // workspace layout (floats); total 53,263,872 floats = 203.2 MiB
  float* ws  = (float*)d_ws;
  float* seq = ws;                    // 8*1034*768 = 6,352,896
  float* z   = seq + 6352896;         // 8*834*768  = 5,124,096
  float* zA  = z + 5124096;           // LN/GN out, also attn-out
  float* Qb  = zA + 5124096;          // Q, later ln3-transposed (n,768,834)
  float* Kb  = Qb + 5124096;
  float* Vb  = Kb + 5124096;
  float* BIG = Vb + 5124096;          // fmid 8*834*3072 = 20,496,384 (aliases tokenize scratch)
  float* gxb = BIG + 20496384;        // 8272*96 = 794,112
  float* w1r  = BIG;                  // 589,824
  float* w2r  = w1r + 589824;         // 1,327,104
  float* colb = w2r + 1327104;        // up to 2,709,504

  // ---- tokenize ----
  resize_w_kernel<<<2304, 256, 0, stream>>>(conv_w, w1r, 16, 4, 4);
  resize_w_kernel<<<5184, 256, 0, stream>>>(conv_w, w2r, 4, 12, 12);

  im2col_kernel<<<9408, 256, 0, stream>>>(x, colb, 1568, 1536, 196, 8, 8, 8, 16, 32, 32);
  gemm_nt<<<dim3(6, 13), 256, 0, stream>>>(colb, 1536, conv_w, 1536, 1568, 768, 1536,
                                           conv_b, nullptr, seq, 1, 196, 1, 768);
  im2col_kernel<<<10584, 256, 0, stream>>>(x, colb, 3528, 768, 441, 16, 4, 4, 6, 32, 32);
  gemm_nt<<<dim3(6, 28), 256, 0, stream>>>(colb, 768, w1r, 768, 3528, 768, 768,
                                           conv_b + 768, nullptr, seq, 1, 441, 197, 768);
  im2col_kernel<<<10584, 256, 0, stream>>>(x, colb, 1568, 1728, 196, 4, 12, 12, 16, 32, 32);
  gemm_nt<<<dim3(6, 13), 256, 0, stream>>>(colb, 1728, w2r, 1728, 1568, 768, 1728,
                                           conv_b + 1536, nullptr, seq, 1, 196, 638, 768);

  addpos_kernel<<<20016, 256, 0, stream>>>(seq, pos_emb, cls_tok);

  // ---- temporal encoder ----
  groupnorm_kernel<<<256, 256, 0, stream>>>(seq, gn_g, gn_b, zA);
  gemm_nt<<<dim3(6, 53), 256, 0, stream>>>(zA, 768, pin_w, 768, 6672, 768, 768,
                                           pin_b, nullptr, z, 0, 0, 0, 768);

  for (int l = 0; l < 2; l++) {
    ln_rows_kernel<<<6672, 256, 0, stream>>>(z, ln_g[l], ln_b[l], zA, 1e-5f);
    gemm_nt<<<dim3(6, 53), 256, 0, stream>>>(zA, 768, wq[l], 768, 6672, 768, 768,
                                             nullptr, nullptr, Qb, 0, 0, 0, 768);
    gemm_nt<<<dim3(6, 53), 256, 0, stream>>>(zA, 768, wk[l], 768, 6672, 768, 768,
                                             nullptr, nullptr, Kb, 0, 0, 0, 768);
    gemm_nt<<<dim3(6, 53), 256, 0, stream>>>(zA, 768, wv[l], 768, 6672, 768, 768,
                                             nullptr, nullptr, Vb, 0, 0, 0, 768);
    attn_kernel<<<dim3(53, 16, 8), 256, 0, stream>>>(Qb, Kb, Vb, zA);
    gemm_nt<<<dim3(6, 53), 256, 0, stream>>>(zA, 768, wo[l], 768, 6672, 768, 768,
                                             bo[l], z, z, 0, 0, 0, 768);
  }

  // ---- FFN (conv1d k=9) ----
  ln_rows_kernel<<<6672, 256, 0, stream>>>(z, ln_g[2], ln_b[2], zA, 1e-5f);
  transpose_tc_kernel<<<dim3(27, 24, 8), 256, 0, stream>>>(zA, Qb);  // (n,768,834)
  gemm_conv1d<<<dim3(24, 53), 256, 0, stream>>>(ff_w1, Qb, 768, 6672, 3072, 6912,
                                                ff_b1, nullptr, BIG, 1);
  gemm_conv1d<<<dim3(6, 53), 256, 0, stream>>>(ff_w2, BIG, 3072, 6672, 768, 27648,
                                               ff_b2, z, z, 2);

  // ---- pout + residual into seq; spa proj into seq tail ----
  gemm_nt<<<dim3(6, 53), 256, 0, stream>>>(z, 768, pout_w, 768, 6672, 768, 768,
                                           pout_b, seq, seq, 1, 834, 0, 768);
  gemm_nt<<<dim3(6, 13), 256, 0, stream>>>(spa_feas, 2048, spa_w, 2048, 1600, 768, 2048,
                                           spa_b, nullptr, seq, 1, 200, 834, 768);

  // ---- GRU input projection + scan + head ----
  gemm_nt<<<dim3(1, 65), 256, 0, stream>>>(seq, 768, gru_wih, 768, 8272, 96, 768,
                                           gru_bih, nullptr, gxb, 0, 0, 0, 96);
  gru_kernel<<<8, 64, 0, stream>>>(gxb, gru_whh, gru_bhh, qh_w, qh_b, fea_len, outp);
}

// Round 2
// 9039.114 us; speedup vs baseline: 1.8840x; 1.8840x over previous
//
#include <hip/hip_runtime.h>

// ---------------------------------------------------------------------------
// Tube_fps model forward. fp32 everywhere except the FFN convs, which run as
// 3-pass split-bf16 MFMA (error ~2^-16 rel).
// Layouts:
//   seq : (8, 1034, 768) rows 0..833 transformer stream, 834..1033 spa
//   z   : (8, 834, 768) residual stream
//   zs  : ln3 stream, bf16 hi/lo planes, rows padded: (8*842+66, 768)
//   fmid: bf16 hi/lo planes, 4-sample slots: (4*842+66, 3072)
// ---------------------------------------------------------------------------

typedef short bf16x8 __attribute__((ext_vector_type(8)));
typedef float f32x4 __attribute__((ext_vector_type(4)));

__device__ __forceinline__ void split_bf16(float f, ushort& h, ushort& l) {
  uint u = __float_as_uint(f);
  uint rh = (u + 0x7FFFu + ((u >> 16) & 1u)) & 0xFFFF0000u;
  h = (ushort)(rh >> 16);
  float fl = f - __uint_as_float(rh);
  uint ul = __float_as_uint(fl);
  l = (ushort)((ul + 0x7FFFu + ((ul >> 16) & 1u)) >> 16);
}

__device__ __forceinline__ float gelu_exact(float v) {
  return 0.5f * v * (1.f + erff(v * 0.70710678118654752f));
}

// ---------------- weight trilinear resize (jax.image.resize, antialias) ----
__device__ __forceinline__ void dim_weights(int j, int O, float* w) {
  float inv = 8.0f / (float)O;
  float ks  = inv > 1.0f ? inv : 1.0f;
  float sf  = ((float)j + 0.5f) * inv - 0.5f;
  float tot = 0.f;
#pragma unroll
  for (int i = 0; i < 8; i++) {
    float xx = fabsf(sf - (float)i) / ks;
    float t  = fmaxf(0.f, 1.f - xx);
    w[i] = t; tot += t;
  }
  float r = 1.f / tot;
#pragma unroll
  for (int i = 0; i < 8; i++) w[i] *= r;
}

__global__ void resize_w_kernel(const float* __restrict__ src, float* __restrict__ dst,
                                int OD, int OH, int OW) {
  int idx = blockIdx.x * 256 + threadIdx.x;
  int tot = 2304 * OD * OH * OW;
  if (idx >= tot) return;
  int ow = idx % OW; int t = idx / OW;
  int oh = t % OH;   t /= OH;
  int od = t % OD;   int oc = t / OD;
  float wd[8], wh[8], ww[8];
  dim_weights(od, OD, wd);
  dim_weights(oh, OH, wh);
  dim_weights(ow, OW, ww);
  const float* s = src + (size_t)oc * 512;
  float acc = 0.f;
  for (int d = 0; d < 8; d++) {
    if (wd[d] == 0.f) continue;
    for (int h = 0; h < 8; h++) {
      if (wh[h] == 0.f) continue;
      float w2 = wd[d] * wh[h];
      for (int w = 0; w < 8; w++) {
        float w3 = w2 * ww[w];
        if (w3 != 0.f) acc += w3 * s[d * 64 + h * 8 + w];
      }
    }
  }
  dst[idx] = acc;
}

// ---------------- im2col for tubelet conv3d --------------------------------
__global__ void im2col_kernel(const float* __restrict__ x, float* __restrict__ col,
                              int P, int K, int L,
                              int KD, int KH, int KW, int SD, int SH, int SW) {
  int idx = blockIdx.x * 256 + threadIdx.x;
  if (idx >= P * K) return;
  int p = idx / K;  int k = idx - p * K;
  int n = p / L;    int lp = p - n * L;
  int ld = lp / 49; int r = lp - ld * 49;
  int lh = r / 7;   int lw = r - lh * 7;
  int kvol = KD * KH * KW;
  int c = k / kvol; int r2 = k - c * kvol;
  int khw = KH * KW;
  int kd = r2 / khw; int r3 = r2 - kd * khw;
  int kh = r3 / KW;  int kw = r3 - kh * KW;
  int zd = ld * SD + kd, zh = lh * SH + kh, zw = lw * SW + kw;
  col[(size_t)p * K + k] =
      x[((((size_t)n * 3 + c) * 64 + zd) * 224 + zh) * 224 + zw];
}

// ---------------- generic fp32 GEMM: C[i][j] = sum_k A[i][k]*B[j][k] -------
__global__ __launch_bounds__(256) void gemm_nt(
    const float* __restrict__ A, int lda,
    const float* __restrict__ B, int ldb,
    int I, int J, int K,
    const float* __restrict__ bias,
    const float* __restrict__ res,
    float* __restrict__ out,
    int map_mode, int map_L, int map_off, int out_ld) {
  __shared__ float As[16 * 136];
  __shared__ float Bs[16 * 136];
  const int tid = threadIdx.x;
  const int i0 = blockIdx.y * 128;
  const int j0 = blockIdx.x * 128;
  const int lr = tid >> 2;
  const int lk = (tid & 3) << 2;
  const int tx = tid & 15;
  const int ty = tid >> 4;
  float acc[8][8];
#pragma unroll
  for (int u = 0; u < 8; u++)
#pragma unroll
    for (int v = 0; v < 8; v++) acc[u][v] = 0.f;

  for (int k0 = 0; k0 < K; k0 += 16) {
    float4 a0 = make_float4(0, 0, 0, 0), a1 = a0, b0 = a0, b1 = a0;
    int ra = i0 + lr;
    if (ra < I)      a0 = *(const float4*)(A + (size_t)ra * lda + (k0 + lk));
    if (ra + 64 < I) a1 = *(const float4*)(A + (size_t)(ra + 64) * lda + (k0 + lk));
    int rb = j0 + lr;
    if (rb < J)      b0 = *(const float4*)(B + (size_t)rb * ldb + (k0 + lk));
    if (rb + 64 < J) b1 = *(const float4*)(B + (size_t)(rb + 64) * ldb + (k0 + lk));
    __syncthreads();
    As[(lk + 0) * 136 + lr] = a0.x; As[(lk + 1) * 136 + lr] = a0.y;
    As[(lk + 2) * 136 + lr] = a0.z; As[(lk + 3) * 136 + lr] = a0.w;
    As[(lk + 0) * 136 + lr + 64] = a1.x; As[(lk + 1) * 136 + lr + 64] = a1.y;
    As[(lk + 2) * 136 + lr + 64] = a1.z; As[(lk + 3) * 136 + lr + 64] = a1.w;
    Bs[(lk + 0) * 136 + lr] = b0.x; Bs[(lk + 1) * 136 + lr] = b0.y;
    Bs[(lk + 2) * 136 + lr] = b0.z; Bs[(lk + 3) * 136 + lr] = b0.w;
    Bs[(lk + 0) * 136 + lr + 64] = b1.x; Bs[(lk + 1) * 136 + lr + 64] = b1.y;
    Bs[(lk + 2) * 136 + lr + 64] = b1.z; Bs[(lk + 3) * 136 + lr + 64] = b1.w;
    __syncthreads();
#pragma unroll
    for (int kk = 0; kk < 16; kk++) {
      float4 aA = *(const float4*)&As[kk * 136 + ty * 4];
      float4 aB = *(const float4*)&As[kk * 136 + 64 + ty * 4];
      float4 bA = *(const float4*)&Bs[kk * 136 + tx * 4];
      float4 bB = *(const float4*)&Bs[kk * 136 + 64 + tx * 4];
      float av[8] = {aA.x, aA.y, aA.z, aA.w, aB.x, aB.y, aB.z, aB.w};
      float bv[8] = {bA.x, bA.y, bA.z, bA.w, bB.x, bB.y, bB.z, bB.w};
#pragma unroll
      for (int u = 0; u < 8; u++)
#pragma unroll
        for (int v = 0; v < 8; v++)
          acc[u][v] = fmaf(av[u], bv[v], acc[u][v]);
    }
  }

#pragma unroll
  for (int u = 0; u < 8; u++) {
    int i = i0 + ty * 4 + (u & 3) + ((u >> 2) << 6);
    if (i >= I) continue;
    size_t rowbase;
    if (map_mode == 0) {
      rowbase = (size_t)i * out_ld;
    } else {
      int nn = i / map_L; int ll = i - nn * map_L;
      rowbase = ((size_t)(nn * 1034 + map_off + ll)) * 768;
    }
#pragma unroll
    for (int v = 0; v < 8; v++) {
      int j = j0 + tx * 4 + (v & 3) + ((v >> 2) << 6);
      if (j >= J) continue;
      float val = acc[u][v];
      if (bias) val += bias[j];
      size_t oi = rowbase + j;
      if (res) val += res[oi];
      out[oi] = val;
    }
  }
}

// ---------------- weight prep: W[o][c*9+dt] fp32 -> [dt][o][c] bf16 hi/lo --
__global__ void wprep_kernel(const float* __restrict__ W, ushort* __restrict__ wh,
                             ushort* __restrict__ wl, int J, int Cin) {
  size_t idx = (size_t)blockIdx.x * 256 + threadIdx.x;
  size_t tot = (size_t)9 * J * Cin;
  if (idx >= tot) return;
  int c = (int)(idx % Cin);
  size_t t2 = idx / Cin;
  int o = (int)(t2 % J);
  int dt = (int)(t2 / J);
  float f = W[(size_t)o * Cin * 9 + (size_t)c * 9 + dt];
  ushort h, l;
  split_bf16(f, h, l);
  wh[idx] = h; wl[idx] = l;
}

// ---------------- ln3 + split into padded bf16 planes ----------------------
__global__ __launch_bounds__(256) void ln_split_kernel(
    const float* __restrict__ in, const float* __restrict__ g,
    const float* __restrict__ b, ushort* __restrict__ oh, ushort* __restrict__ ol) {
  int row = blockIdx.x, tid = threadIdx.x;   // row in [0, 6672)
  int n = row / 834, t = row - n * 834;
  const float* xp = in + (size_t)row * 768;
  float v0 = xp[tid], v1 = xp[tid + 256], v2 = xp[tid + 512];
  float s = v0 + v1 + v2;
  float sq = v0 * v0 + v1 * v1 + v2 * v2;
  __shared__ float red[8];
#pragma unroll
  for (int off = 32; off >= 1; off >>= 1) {
    s += __shfl_down(s, off, 64); sq += __shfl_down(sq, off, 64);
  }
  if ((tid & 63) == 0) { red[tid >> 6] = s; red[4 + (tid >> 6)] = sq; }
  __syncthreads();
  s = red[0] + red[1] + red[2] + red[3];
  sq = red[4] + red[5] + red[6] + red[7];
  float m = s * (1.f / 768.f);
  float var = sq * (1.f / 768.f) - m * m;
  float rs = rsqrtf(var + 1e-5f);
  size_t dbase = ((size_t)(n * 842 + 4 + t)) * 768;
  ushort h, l;
  float y0 = (v0 - m) * rs * g[tid] + b[tid];
  split_bf16(y0, h, l); oh[dbase + tid] = h; ol[dbase + tid] = l;
  float y1 = (v1 - m) * rs * g[tid + 256] + b[tid + 256];
  split_bf16(y1, h, l); oh[dbase + tid + 256] = h; ol[dbase + tid + 256] = l;
  float y2 = (v2 - m) * rs * g[tid + 512] + b[tid + 512];
  split_bf16(y2, h, l); oh[dbase + tid + 512] = h; ol[dbase + tid + 512] = l;
}

// ---------------- zero the pad rows of zs (8 samples) and fmid (4 slots) ---
__global__ void pad_zero_kernel(ushort* __restrict__ zh, ushort* __restrict__ zl,
                                ushort* __restrict__ fh, ushort* __restrict__ fl) {
  int idx = blockIdx.x * 256 + threadIdx.x;
  if (idx < 49152) {  // zs: 8n * 8 rows * 768
    int c = idx % 768; int t2 = idx / 768;
    int rr = t2 & 7; int n = t2 >> 3;
    int row = (rr < 4) ? rr : (834 + rr);
    size_t d = ((size_t)(n * 842 + row)) * 768 + c;
    zh[d] = 0; zl[d] = 0;
  } else {
    int k = idx - 49152;            // fmid: 4 slots * 8 rows * 3072
    if (k >= 98304) return;
    int c = k % 3072; int t2 = k / 3072;
    int rr = t2 & 7; int sl = t2 >> 3;
    int row = (rr < 4) ? rr : (834 + rr);
    size_t d = ((size_t)(sl * 842 + row)) * 3072 + c;
    fh[d] = 0; fl[d] = 0;
  }
}

// ---------------- conv1d-as-9-shifted-GEMMs, 3-pass split-bf16 MFMA --------
// BM=128 t-rows per block. A: stream planes (rows = an*842 + t), k = Cin.
// W planes: [dt][J][Cin]. MODE 1: GELU -> bf16 hi/lo planes (slot rows).
// MODE 2: fp32 out = acc + bias + res  (z layout (n,834,768)).
template <int BN, int WM, int WN, int MODE>
__global__ __launch_bounds__(256) void conv_mfma(
    const ushort* __restrict__ Ah, const ushort* __restrict__ Al,
    const ushort* __restrict__ Wh, const ushort* __restrict__ Wl,
    int Cin, int J, int n0,
    const float* __restrict__ bias,
    ushort* __restrict__ oh, ushort* __restrict__ ol,
    float* __restrict__ of, const float* __restrict__ res) {
  const int MI = WM / 16, NI = WN / 16;
  __shared__ ushort ldsA[2 * 136 * 40];
  __shared__ ushort ldsB[2 * BN * 40];
  const int tid = threadIdx.x;
  const int wave = tid >> 6, lane = tid & 63;
  const int lrow = lane & 15, kq = lane >> 4;
  const int t0 = blockIdx.x * 128;
  const int j0 = blockIdx.y * BN;
  const int bz = blockIdx.z;
  const int n_real = n0 + bz;
  const int an = (MODE == 1) ? n_real : bz;   // A plane sample index
  const int wm = (wave & 1) * WM;
  const int wn = (wave >> 1) * WN;

  f32x4 acc[MI][NI];
#pragma unroll
  for (int mi = 0; mi < MI; mi++)
#pragma unroll
    for (int ni = 0; ni < NI; ni++) acc[mi][ni] = (f32x4)0.f;

  for (int c0 = 0; c0 < Cin; c0 += 32) {
    __syncthreads();
    // stage A: 136 rows x 32 c, hi+lo
    for (int task = tid; task < 544; task += 256) {
      int plane = task >= 272;
      int rem = task - plane * 272;
      int r = rem >> 1, h = rem & 1;
      const ushort* src = (plane ? Al : Ah) +
          ((size_t)(an * 842 + t0 + r)) * Cin + c0 + h * 16;
      uint4 d0 = *(const uint4*)(const void*)src;
      uint4 d1 = *(const uint4*)(const void*)(src + 8);
      ushort* dst = &ldsA[plane * 5440 + r * 40 + h * 16];
      *(uint4*)(void*)dst = d0;
      *(uint4*)(void*)(dst + 8) = d1;
    }
    for (int dt = 0; dt < 9; dt++) {
      if (dt > 0) __syncthreads();
      // stage B: BN rows x 32 c, hi+lo (pre-converted weights, pure copy)
      for (int task = tid; task < 4 * BN; task += 256) {
        int plane = task >= 2 * BN;
        int rem = task - plane * 2 * BN;
        int o = rem >> 1, h = rem & 1;
        const ushort* src = (plane ? Wl : Wh) +
            ((size_t)(dt * J + j0 + o)) * Cin + c0 + h * 16;
        uint4 d0 = *(const uint4*)(const void*)src;
        uint4 d1 = *(const uint4*)(const void*)(src + 8);
        ushort* dst = &ldsB[plane * (BN * 40) + o * 40 + h * 16];
        *(uint4*)(void*)dst = d0;
        *(uint4*)(void*)(dst + 8) = d1;
      }
      __syncthreads();
      bf16x8 af[2][MI], bf[2][NI];
#pragma unroll
      for (int p = 0; p < 2; p++)
#pragma unroll
        for (int mi = 0; mi < MI; mi++)
          af[p][mi] = *(const bf16x8*)&ldsA[p * 5440 +
              (dt + wm + mi * 16 + lrow) * 40 + kq * 8];
#pragma unroll
      for (int p = 0; p < 2; p++)
#pragma unroll
        for (int ni = 0; ni < NI; ni++)
          bf[p][ni] = *(const bf16x8*)&ldsB[p * (BN * 40) +
              (wn + ni * 16 + lrow) * 40 + kq * 8];
      // pass hh
#pragma unroll
      for (int mi = 0; mi < MI; mi++)
#pragma unroll
        for (int ni = 0; ni < NI; ni++)
          acc[mi][ni] = __builtin_amdgcn_mfma_f32_16x16x32_bf16(
              af[0][mi], bf[0][ni], acc[mi][ni], 0, 0, 0);
      // pass h*lo(B)
#pragma unroll
      for (int mi = 0; mi < MI; mi++)
#pragma unroll
        for (int ni = 0; ni < NI; ni++)
          acc[mi][ni] = __builtin_amdgcn_mfma_f32_16x16x32_bf16(
              af[0][mi], bf[1][ni], acc[mi][ni], 0, 0, 0);
      // pass lo(A)*h
#pragma unroll
      for (int mi = 0; mi < MI; mi++)
#pragma unroll
        for (int ni = 0; ni < NI; ni++)
          acc[mi][ni] = __builtin_amdgcn_mfma_f32_16x16x32_bf16(
              af[1][mi], bf[0][ni], acc[mi][ni], 0, 0, 0);
    }
  }

  // epilogue. D layout: row(m) = (lane>>4)*4 + reg, col(n) = lane&15
#pragma unroll
  for (int ni = 0; ni < NI; ni++) {
    int o = j0 + wn + ni * 16 + lrow;
    float bo = bias[o];
#pragma unroll
    for (int mi = 0; mi < MI; mi++) {
#pragma unroll
      for (int r = 0; r < 4; r++) {
        int t = t0 + wm + mi * 16 + kq * 4 + r;
        if (t < 834) {
          float v = acc[mi][ni][r] + bo;
          if (MODE == 1) {
            v = gelu_exact(v);
            ushort h, l;
            split_bf16(v, h, l);
            size_t d = ((size_t)(bz * 842 + 4 + t)) * 3072 + o;
            oh[d] = h; ol[d] = l;
          } else {
            size_t d = ((size_t)(n_real * 834 + t)) * 768 + o;
            of[d] = v + res[d];
          }
        }
      }
    }
  }
}

// ---------------- cls/pos add ----------------------------------------------
__global__ void addpos_kernel(float* __restrict__ seq, const float* __restrict__ pos,
                              const float* __restrict__ cls) {
  int idx = blockIdx.x * 256 + threadIdx.x;
  if (idx >= 8 * 834 * 768) return;
  int c = idx % 768;
  int t = (idx / 768) % 834;
  int n = idx / (768 * 834);
  size_t off = ((size_t)(n * 1034 + t)) * 768 + c;
  float v = (t == 0) ? cls[c] : seq[off];
  seq[off] = v + pos[(size_t)t * 768 + c];
}

// ---------------- GroupNorm (32 groups, eps 1e-6) over seq rows 0..833 -----
__global__ __launch_bounds__(256) void groupnorm_kernel(
    const float* __restrict__ seq, const float* __restrict__ g,
    const float* __restrict__ b, float* __restrict__ out) {
  int blk = blockIdx.x;
  int n = blk >> 5, grp = blk & 31;
  int tid = threadIdx.x;
  float s = 0.f, sq = 0.f;
  for (int e = tid; e < 20016; e += 256) {
    int t = e / 24; int cc = e - t * 24;
    float v = seq[((size_t)(n * 1034 + t)) * 768 + grp * 24 + cc];
    s += v; sq += v * v;
  }
  __shared__ float red[8];
#pragma unroll
  for (int off = 32; off >= 1; off >>= 1) {
    s += __shfl_down(s, off, 64); sq += __shfl_down(sq, off, 64);
  }
  if ((tid & 63) == 0) { red[tid >> 6] = s; red[4 + (tid >> 6)] = sq; }
  __syncthreads();
  s = red[0] + red[1] + red[2] + red[3];
  sq = red[4] + red[5] + red[6] + red[7];
  float m = s * (1.f / 20016.f);
  float var = sq * (1.f / 20016.f) - m * m;
  float rs = rsqrtf(var + 1e-6f);
  for (int e = tid; e < 20016; e += 256) {
    int t = e / 24; int cc = e - t * 24;
    int c = grp * 24 + cc;
    float v = seq[((size_t)(n * 1034 + t)) * 768 + c];
    out[((size_t)(n * 834 + t)) * 768 + c] = (v - m) * rs * g[c] + b[c];
  }
}

// ---------------- LayerNorm per row of 768 ---------------------------------
__global__ __launch_bounds__(256) void ln_rows_kernel(
    const float* __restrict__ in, const float* __restrict__ g,
    const float* __restrict__ b, float* __restrict__ out, float eps) {
  int row = blockIdx.x, tid = threadIdx.x;
  const float* xp = in + (size_t)row * 768;
  float v0 = xp[tid], v1 = xp[tid + 256], v2 = xp[tid + 512];
  float s = v0 + v1 + v2;
  float sq = v0 * v0 + v1 * v1 + v2 * v2;
  __shared__ float red[8];
#pragma unroll
  for (int off = 32; off >= 1; off >>= 1) {
    s += __shfl_down(s, off, 64); sq += __shfl_down(sq, off, 64);
  }
  if ((tid & 63) == 0) { red[tid >> 6] = s; red[4 + (tid >> 6)] = sq; }
  __syncthreads();
  s = red[0] + red[1] + red[2] + red[3];
  sq = red[4] + red[5] + red[6] + red[7];
  float m = s * (1.f / 768.f);
  float var = sq * (1.f / 768.f) - m * m;
  float rs = rsqrtf(var + eps);
  float* op = out + (size_t)row * 768;
  op[tid]       = (v0 - m) * rs * g[tid]       + b[tid];
  op[tid + 256] = (v1 - m) * rs * g[tid + 256] + b[tid + 256];
  op[tid + 512] = (v2 - m) * rs * g[tid + 512] + b[tid + 512];
}

// ---------------- flash attention (fp32, online softmax) -------------------
__global__ __launch_bounds__(256) void attn_kernel(
    const float* __restrict__ Q, const float* __restrict__ K,
    const float* __restrict__ V, float* __restrict__ O) {
  const int S = 834;
  __shared__ float Qs[16][49];
  __shared__ float Ks[64][49];
  __shared__ float Vs[64][49];
  __shared__ float Ps[16][64];
  const int tid = threadIdx.x;
  const int r = tid >> 4;
  const int cg = tid & 15;
  const int qb = blockIdx.x, head = blockIdx.y, n = blockIdx.z;
  const int qi = qb * 16 + r;
  const size_t base = ((size_t)n * S) * 768 + head * 48;
#pragma unroll
  for (int u = 0; u < 3; u++) {
    int d = cg * 3 + u;
    Qs[r][d] = (qi < S) ? Q[base + (size_t)qi * 768 + d] : 0.f;
  }
  float m_i = -1e30f, l_i = 0.f;
  float av0 = 0.f, av1 = 0.f, av2 = 0.f;
  __syncthreads();
  for (int kt = 0; kt < S; kt += 64) {
    int kn = S - kt; if (kn > 64) kn = 64;
    for (int e = tid; e < 64 * 48; e += 256) {
      int kk = e / 48, d = e - kk * 48;
      int ki = kt + kk;
      float kv = 0.f, vv = 0.f;
      if (ki < S) {
        kv = K[base + (size_t)ki * 768 + d];
        vv = V[base + (size_t)ki * 768 + d];
      }
      Ks[kk][d] = kv; Vs[kk][d] = vv;
    }
    __syncthreads();
    float s0 = 0, s1 = 0, s2 = 0, s3 = 0;
#pragma unroll 8
    for (int d = 0; d < 48; d++) {
      float qd = Qs[r][d];
      s0 = fmaf(qd, Ks[cg][d], s0);
      s1 = fmaf(qd, Ks[cg + 16][d], s1);
      s2 = fmaf(qd, Ks[cg + 32][d], s2);
      s3 = fmaf(qd, Ks[cg + 48][d], s3);
    }
    const float sc = 0.14433756729740644f;
    s0 = (cg      < kn) ? s0 * sc : -1e30f;
    s1 = (cg + 16 < kn) ? s1 * sc : -1e30f;
    s2 = (cg + 32 < kn) ? s2 * sc : -1e30f;
    s3 = (cg + 48 < kn) ? s3 * sc : -1e30f;
    float mloc = fmaxf(fmaxf(s0, s1), fmaxf(s2, s3));
#pragma unroll
    for (int off = 8; off >= 1; off >>= 1)
      mloc = fmaxf(mloc, __shfl_xor(mloc, off, 16));
    float mnew = fmaxf(m_i, mloc);
    float p0 = expf(s0 - mnew), p1 = expf(s1 - mnew);
    float p2 = expf(s2 - mnew), p3 = expf(s3 - mnew);
    float ps = p0 + p1 + p2 + p3;
#pragma unroll
    for (int off = 8; off >= 1; off >>= 1) ps += __shfl_xor(ps, off, 16);
    float alpha = expf(m_i - mnew);
    l_i = l_i * alpha + ps;
    av0 *= alpha; av1 *= alpha; av2 *= alpha;
    Ps[r][cg] = p0; Ps[r][cg + 16] = p1; Ps[r][cg + 32] = p2; Ps[r][cg + 48] = p3;
    m_i = mnew;
    int d0 = cg * 3;
#pragma unroll 4
    for (int k4 = 0; k4 < 16; k4++) {
      float4 pv = *(const float4*)&Ps[r][k4 * 4];
      av0 = fmaf(pv.x, Vs[k4 * 4 + 0][d0 + 0], av0);
      av1 = fmaf(pv.x, Vs[k4 * 4 + 0][d0 + 1], av1);
      av2 = fmaf(pv.x, Vs[k4 * 4 + 0][d0 + 2], av2);
      av0 = fmaf(pv.y, Vs[k4 * 4 + 1][d0 + 0], av0);
      av1 = fmaf(pv.y, Vs[k4 * 4 + 1][d0 + 1], av1);
      av2 = fmaf(pv.y, Vs[k4 * 4 + 1][d0 + 2], av2);
      av0 = fmaf(pv.z, Vs[k4 * 4 + 2][d0 + 0], av0);
      av1 = fmaf(pv.z, Vs[k4 * 4 + 2][d0 + 1], av1);
      av2 = fmaf(pv.z, Vs[k4 * 4 + 2][d0 + 2], av2);
      av0 = fmaf(pv.w, Vs[k4 * 4 + 3][d0 + 0], av0);
      av1 = fmaf(pv.w, Vs[k4 * 4 + 3][d0 + 1], av1);
      av2 = fmaf(pv.w, Vs[k4 * 4 + 3][d0 + 2], av2);
    }
    __syncthreads();
  }
  if (qi < S) {
    float inv = 1.f / l_i;
    O[base + (size_t)qi * 768 + cg * 3 + 0] = av0 * inv;
    O[base + (size_t)qi * 768 + cg * 3 + 1] = av1 * inv;
    O[base + (size_t)qi * 768 + cg * 3 + 2] = av2 * inv;
  }
}

// ---------------- GRU (torch cell) + masked-mean head, 1 wave / sample -----
__global__ __launch_bounds__(64) void gru_kernel(
    const float* __restrict__ gx, const float* __restrict__ whh,
    const float* __restrict__ bhh, const float* __restrict__ qh_w,
    const float* __restrict__ qh_b, const int* __restrict__ fea_len,
    float* __restrict__ out) {
  int n = blockIdx.x;
  int lane = threadIdx.x;
  bool lo = lane < 32;
  float w1[32], w2[32];
#pragma unroll
  for (int i = 0; i < 32; i++) w1[i] = whh[lane * 32 + i];
#pragma unroll
  for (int i = 0; i < 32; i++) w2[i] = lo ? whh[(64 + lane) * 32 + i] : 0.f;
  float bh1 = bhh[lane];
  float bh2 = lo ? bhh[64 + lane] : 0.f;
  float qw  = lo ? qh_w[lane] : 0.f;
  float h_all[32];
#pragma unroll
  for (int i = 0; i < 32; i++) h_all[i] = 0.f;
  float hown = 0.f, acc = 0.f;
  int L = fea_len[n] + 834;
  const float* gb = gx + (size_t)n * 1034 * 96;
  for (int t = 0; t < 1034; t++) {
    if (t >= L) break;
    const float* g = gb + (size_t)t * 96;
    float g1 = g[lane];
    float g2 = lo ? g[64 + lane] : 0.f;
    float gh1 = bh1, gh2 = bh2;
#pragma unroll
    for (int i = 0; i < 32; i++) {
      gh1 = fmaf(h_all[i], w1[i], gh1);
      gh2 = fmaf(h_all[i], w2[i], gh2);
    }
    float s1 = g1 + gh1;
    float szg = __shfl(s1, (lane + 32) & 63, 64);
    float rg = 1.f / (1.f + expf(-s1));
    float zg = 1.f / (1.f + expf(-szg));
    float nn = tanhf(fmaf(rg, gh2, g2));
    float hn = (1.f - zg) * nn + zg * hown;
    if (lo) { hown = hn; acc = fmaf(hn, qw, acc); }
#pragma unroll
    for (int i = 0; i < 32; i++) h_all[i] = __shfl(hn, i, 64);
  }
#pragma unroll
  for (int off = 16; off >= 1; off >>= 1) acc += __shfl_down(acc, off, 64);
  if (lane == 0) out[n] = acc / (float)L + qh_b[0];
}

// ---------------------------------------------------------------------------
extern "C" void kernel_launch(void* const* d_in, const int* in_sizes, int n_in,
                              void* d_out, int out_size, void* d_ws, size_t ws_size,
                              hipStream_t stream) {
  const float* x        = (const float*)d_in[0];
  const float* spa_feas = (const float*)d_in[1];
  const int*   fea_len  = (const int*)d_in[2];
  const float* pos_emb  = (const float*)d_in[3];
  const float* cls_tok  = (const float*)d_in[4];
  const float* conv_w   = (const float*)d_in[5];
  const float* conv_b   = (const float*)d_in[6];
  const float* gn_g     = (const float*)d_in[7];
  const float* gn_b     = (const float*)d_in[8];
  const float* pin_w    = (const float*)d_in[9];
  const float* pin_b    = (const float*)d_in[10];
  const float* ln_g[3]  = {(const float*)d_in[11], (const float*)d_in[13], (const float*)d_in[15]};
  const float* ln_b[3]  = {(const float*)d_in[12], (const float*)d_in[14], (const float*)d_in[16]};
  const float* wq[2] = {(const float*)d_in[17], (const float*)d_in[22]};
  const float* wk[2] = {(const float*)d_in[18], (const float*)d_in[23]};
  const float* wv[2] = {(const float*)d_in[19], (const float*)d_in[24]};
  const float* wo[2] = {(const float*)d_in[20], (const float*)d_in[25]};
  const float* bo[2] = {(const float*)d_in[21], (const float*)d_in[26]};
  const float* ff_w1 = (const float*)d_in[27];
  const float* ff_b1 = (const float*)d_in[28];
  const float* ff_w2 = (const float*)d_in[29];
  const float* ff_b2 = (const float*)d_in[30];
  const float* pout_w = (const float*)d_in[31];
  const float* pout_b = (const float*)d_in[32];
  const float* spa_w  = (const float*)d_in[33];
  const float* spa_b  = (const float*)d_in[34];
  const float* gru_wih = (const float*)d_in[35];
  const float* gru_whh = (const float*)d_in[36];
  const float* gru_bih = (const float*)d_in[37];
  const float* gru_bhh = (const float*)d_in[38];
  const float* qh_w = (const float*)d_in[39];
  const float* qh_b = (const float*)d_in[40];
  float* outp = (float*)d_out;

  // ---- workspace layout (floats), total 53,263,872 (same as r1) ----
  float* ws  = (float*)d_ws;
  float* seq = ws;                         // 6,352,896
  float* z   = seq + 6352896;              // 5,124,096 -> ends 11,476,992
  float* zA  = z + 5124096;                // 5,124,096 (attn scratch / LN out)
  float* S1  = zA + 5124096;               // Qb
  float* S2  = S1 + 5124096;               // Kb
  float* S3  = S2 + 5124096;               // Vb -> ends 31,973,376
  float* BR  = ws + 31973376;              // 21,290,496 floats big region

  // FFN-phase aliases over [zA .. S3 end) = 20,496,384 floats = 40,992,768 ushorts
  ushort* pool = (ushort*)zA;
  ushort* zsH = pool;                      // (8*842+66)*768 = 5,223,936
  ushort* zsL = zsH + 5223936;
  ushort* fH  = zsL + 5223936;             // (4*842+66)*3072 = 10,549,248
  ushort* fL  = fH + 10549248;             // ends 31,546,368 <= 40,992,768 OK
  // BR aliases
  float* w1r  = BR;                        // 589,824
  float* w2r  = w1r + 589824;              // 1,327,104
  float* colb = w2r + 1327104;             // <= 2,709,504
  ushort* wH  = (ushort*)BR;               // 21,233,664 ushorts (weight planes)
  ushort* wL  = wH + 21233664;             // total = 21,233,664 floats <= BR
  float* gxb  = BR;                        // 794,112 (after convs)

  // ---- tokenize ----
  resize_w_kernel<<<2304, 256, 0, stream>>>(conv_w, w1r, 16, 4, 4);
  resize_w_kernel<<<5184, 256, 0, stream>>>(conv_w, w2r, 4, 12, 12);

  im2col_kernel<<<9408, 256, 0, stream>>>(x, colb, 1568, 1536, 196, 8, 8, 8, 16, 32, 32);
  gemm_nt<<<dim3(6, 13), 256, 0, stream>>>(colb, 1536, conv_w, 1536, 1568, 768, 1536,
                                           conv_b, nullptr, seq, 1, 196, 1, 768);
  im2col_kernel<<<10584, 256, 0, stream>>>(x, colb, 3528, 768, 441, 16, 4, 4, 6, 32, 32);
  gemm_nt<<<dim3(6, 28), 256, 0, stream>>>(colb, 768, w1r, 768, 3528, 768, 768,
                                           conv_b + 768, nullptr, seq, 1, 441, 197, 768);
  im2col_kernel<<<10584, 256, 0, stream>>>(x, colb, 1568, 1728, 196, 4, 12, 12, 16, 32, 32);
  gemm_nt<<<dim3(6, 13), 256, 0, stream>>>(colb, 1728, w2r, 1728, 1568, 768, 1728,
                                           conv_b + 1536, nullptr, seq, 1, 196, 638, 768);

  addpos_kernel<<<20016, 256, 0, stream>>>(seq, pos_emb, cls_tok);

  // ---- temporal encoder front ----
  groupnorm_kernel<<<256, 256, 0, stream>>>(seq, gn_g, gn_b, zA);
  gemm_nt<<<dim3(6, 53), 256, 0, stream>>>(zA, 768, pin_w, 768, 6672, 768, 768,
                                           pin_b, nullptr, z, 0, 0, 0, 768);

  for (int l = 0; l < 2; l++) {
    ln_rows_kernel<<<6672, 256, 0, stream>>>(z, ln_g[l], ln_b[l], zA, 1e-5f);
    gemm_nt<<<dim3(6, 53), 256, 0, stream>>>(zA, 768, wq[l], 768, 6672, 768, 768,
                                             nullptr, nullptr, S1, 0, 0, 0, 768);
    gemm_nt<<<dim3(6, 53), 256, 0, stream>>>(zA, 768, wk[l], 768, 6672, 768, 768,
                                             nullptr, nullptr, S2, 0, 0, 0, 768);
    gemm_nt<<<dim3(6, 53), 256, 0, stream>>>(zA, 768, wv[l], 768, 6672, 768, 768,
                                             nullptr, nullptr, S3, 0, 0, 0, 768);
    attn_kernel<<<dim3(53, 16, 8), 256, 0, stream>>>(S1, S2, S3, zA);
    gemm_nt<<<dim3(6, 53), 256, 0, stream>>>(zA, 768, wo[l], 768, 6672, 768, 768,
                                             bo[l], z, z, 0, 0, 0, 768);
  }

  // ---- FFN (conv1d k=9) via split-bf16 MFMA, two n-halves ----
  ln_split_kernel<<<6672, 256, 0, stream>>>(z, ln_g[2], ln_b[2], zsH, zsL);
  pad_zero_kernel<<<576, 256, 0, stream>>>(zsH, zsL, fH, fL);
  for (int half = 0; half < 2; half++) {
    int n0 = half * 4;
    wprep_kernel<<<82944, 256, 0, stream>>>(ff_w1, wH, wL, 3072, 768);
    conv_mfma<128, 64, 64, 1><<<dim3(7, 24, 4), 256, 0, stream>>>(
        zsH, zsL, wH, wL, 768, 3072, n0, ff_b1, fH, fL, nullptr, nullptr);
    wprep_kernel<<<82944, 256, 0, stream>>>(ff_w2, wH, wL, 768, 3072);
    conv_mfma<64, 64, 32, 2><<<dim3(7, 12, 4), 256, 0, stream>>>(
        fH, fL, wH, wL, 3072, 768, n0, ff_b2, nullptr, nullptr, z, z);
  }

  // ---- pout + residual into seq; spa proj into seq tail ----
  gemm_nt<<<dim3(6, 53), 256, 0, stream>>>(z, 768, pout_w, 768, 6672, 768, 768,
                                           pout_b, seq, seq, 1, 834, 0, 768);
  gemm_nt<<<dim3(6, 13), 256, 0, stream>>>(spa_feas, 2048, spa_w, 2048, 1600, 768, 2048,
                                           spa_b, nullptr, seq, 1, 200, 834, 768);

  // ---- GRU input projection + scan + head ----
  gemm_nt<<<dim3(1, 65), 256, 0, stream>>>(seq, 768, gru_wih, 768, 8272, 96, 768,
                                           gru_bih, nullptr, gxb, 0, 0, 0, 96);
  gru_kernel<<<8, 64, 0, stream>>>(gxb, gru_whh, gru_bhh, qh_w, qh_b, fea_len, outp);
}

// Round 3
// 6287.367 us; speedup vs baseline: 2.7086x; 1.4377x over previous
//
#include <hip/hip_runtime.h>

// ---------------------------------------------------------------------------
// Tube_fps forward. All GEMM-shaped compute on split-bf16 3-pass MFMA
// (x = hi + lo bf16; acc += Ah*Bh + Ah*Bl + Al*Bh; dropped term ~2^-16 rel).
// Attention: MFMA flash, P stored hi-only (err ~0.2% on attn out, diluted).
// fp32 state: seq (8,1034,768), z (8,834,768). Everything else bf16 planes.
// ---------------------------------------------------------------------------

typedef short bf16x8 __attribute__((ext_vector_type(8)));
typedef float f32x4 __attribute__((ext_vector_type(4)));

__device__ __forceinline__ void split_bf16(float f, ushort& h, ushort& l) {
  uint u = __float_as_uint(f);
  uint rh = (u + 0x7FFFu + ((u >> 16) & 1u)) & 0xFFFF0000u;
  h = (ushort)(rh >> 16);
  float fl = f - __uint_as_float(rh);
  uint ul = __float_as_uint(fl);
  l = (ushort)((ul + 0x7FFFu + ((ul >> 16) & 1u)) >> 16);
}

__device__ __forceinline__ ushort bf16_rnd(float f) {
  uint u = __float_as_uint(f);
  return (ushort)((u + 0x7FFFu + ((u >> 16) & 1u)) >> 16);
}

__device__ __forceinline__ float gelu_exact(float v) {
  return 0.5f * v * (1.f + erff(v * 0.70710678118654752f));
}

// ---------------- generic fp32 -> bf16 hi/lo split -------------------------
__global__ void wsplit_kernel(const float* __restrict__ src, ushort* __restrict__ h,
                              ushort* __restrict__ l, int n4) {
  int i = blockIdx.x * 256 + threadIdx.x;
  if (i >= n4) return;
  float4 v = *(const float4*)(src + (size_t)i * 4);
  ushort hh[4], ll[4];
  split_bf16(v.x, hh[0], ll[0]);
  split_bf16(v.y, hh[1], ll[1]);
  split_bf16(v.z, hh[2], ll[2]);
  split_bf16(v.w, hh[3], ll[3]);
  *(ushort4*)(h + (size_t)i * 4) = make_ushort4(hh[0], hh[1], hh[2], hh[3]);
  *(ushort4*)(l + (size_t)i * 4) = make_ushort4(ll[0], ll[1], ll[2], ll[3]);
}

// ---------------- weight trilinear resize (jax.image.resize, antialias) ----
__device__ __forceinline__ void dim_weights(int j, int O, float* w) {
  float inv = 8.0f / (float)O;
  float ks  = inv > 1.0f ? inv : 1.0f;
  float sf  = ((float)j + 0.5f) * inv - 0.5f;
  float tot = 0.f;
#pragma unroll
  for (int i = 0; i < 8; i++) {
    float xx = fabsf(sf - (float)i) / ks;
    float t  = fmaxf(0.f, 1.f - xx);
    w[i] = t; tot += t;
  }
  float r = 1.f / tot;
#pragma unroll
  for (int i = 0; i < 8; i++) w[i] *= r;
}

__global__ void resize_w_split(const float* __restrict__ src, ushort* __restrict__ dh,
                               ushort* __restrict__ dl, int OD, int OH, int OW) {
  int idx = blockIdx.x * 256 + threadIdx.x;
  int tot = 2304 * OD * OH * OW;
  if (idx >= tot) return;
  int ow = idx % OW; int t = idx / OW;
  int oh = t % OH;   t /= OH;
  int od = t % OD;   int oc = t / OD;
  float wd[8], wh[8], ww[8];
  dim_weights(od, OD, wd);
  dim_weights(oh, OH, wh);
  dim_weights(ow, OW, ww);
  const float* s = src + (size_t)oc * 512;
  float acc = 0.f;
  for (int d = 0; d < 8; d++) {
    if (wd[d] == 0.f) continue;
    for (int h = 0; h < 8; h++) {
      if (wh[h] == 0.f) continue;
      float w2 = wd[d] * wh[h];
      for (int w = 0; w < 8; w++) {
        float w3 = w2 * ww[w];
        if (w3 != 0.f) acc += w3 * s[d * 64 + h * 8 + w];
      }
    }
  }
  ushort h2, l2;
  split_bf16(acc, h2, l2);
  dh[idx] = h2; dl[idx] = l2;
}

// ---------------- im2col (split output) ------------------------------------
__global__ void im2col_split(const float* __restrict__ x, ushort* __restrict__ colh,
                             ushort* __restrict__ coll, int P, int K, int L,
                             int KD, int KH, int KW, int SD, int SH, int SW) {
  int idx = blockIdx.x * 256 + threadIdx.x;
  if (idx >= P * K) return;
  int p = idx / K;  int k = idx - p * K;
  int n = p / L;    int lp = p - n * L;
  int ld = lp / 49; int r = lp - ld * 49;
  int lh = r / 7;   int lw = r - lh * 7;
  int kvol = KD * KH * KW;
  int c = k / kvol; int r2 = k - c * kvol;
  int khw = KH * KW;
  int kd = r2 / khw; int r3 = r2 - kd * khw;
  int kh = r3 / KW;  int kw = r3 - kh * KW;
  int zd = ld * SD + kd, zh = lh * SH + kh, zw = lw * SW + kw;
  float v = x[((((size_t)n * 3 + c) * 64 + zd) * 224 + zh) * 224 + zw];
  ushort h, l;
  split_bf16(v, h, l);
  colh[(size_t)p * K + k] = h;
  coll[(size_t)p * K + k] = l;
}

// ---------------- split-bf16 3-pass MFMA GEMM ------------------------------
// C[i][j] = sum_k A[i][k]*B[j][k].  A: M x K planes, B: N x K planes.
// MODE 0: of[i*ldo+j] = acc (+bias)
// MODE 1: of[i*768+j] = acc + bias + res[i*768+j]
// MODE 2: split(acc*scale) -> oh/ol[i*768+j]
// MODE 3: row = (i/mapL)*1034 + mapOff + i%mapL; v = acc + bias (+res[row*768+j]);
//         of[row*768+j] = v; if oh: split v -> oh/ol[row*768+j]
template <int MODE>
__global__ __launch_bounds__(256) void gemm_bf3(
    const ushort* __restrict__ Ah, const ushort* __restrict__ Al,
    const ushort* __restrict__ Bh, const ushort* __restrict__ Bl,
    int M, int N, int K,
    const float* __restrict__ bias, const float* __restrict__ res, float scale,
    float* __restrict__ of, ushort* __restrict__ oh, ushort* __restrict__ ol,
    int mapL, int mapOff, int ldo) {
  __shared__ ushort ldsA[2 * 128 * 40];
  __shared__ ushort ldsB[2 * 128 * 40];
  const int tid = threadIdx.x;
  const int wave = tid >> 6, lane = tid & 63;
  const int lrow = lane & 15, kq = lane >> 4;
  const int i0 = blockIdx.y * 128;
  const int j0 = blockIdx.x * 128;
  const int wm = (wave & 1) * 64, wn = (wave >> 1) * 64;
  const int sr = tid >> 1, sp = tid & 1;

  f32x4 acc[4][4];
#pragma unroll
  for (int mi = 0; mi < 4; mi++)
#pragma unroll
    for (int ni = 0; ni < 4; ni++) acc[mi][ni] = (f32x4)0.f;

  for (int k0 = 0; k0 < K; k0 += 32) {
    __syncthreads();
    {
      uint4 d0 = make_uint4(0, 0, 0, 0), d1 = d0, d2 = d0, d3 = d0;
      if (i0 + sr < M) {
        const ushort* s = (sp ? Al : Ah) + (size_t)(i0 + sr) * K + k0;
        d0 = *(const uint4*)(const void*)s;
        d1 = *(const uint4*)(const void*)(s + 8);
        d2 = *(const uint4*)(const void*)(s + 16);
        d3 = *(const uint4*)(const void*)(s + 24);
      }
      ushort* dst = &ldsA[sp * 5120 + sr * 40];
      *(uint4*)(void*)dst = d0; *(uint4*)(void*)(dst + 8) = d1;
      *(uint4*)(void*)(dst + 16) = d2; *(uint4*)(void*)(dst + 24) = d3;
    }
    {
      uint4 d0 = make_uint4(0, 0, 0, 0), d1 = d0, d2 = d0, d3 = d0;
      if (j0 + sr < N) {
        const ushort* s = (sp ? Bl : Bh) + (size_t)(j0 + sr) * K + k0;
        d0 = *(const uint4*)(const void*)s;
        d1 = *(const uint4*)(const void*)(s + 8);
        d2 = *(const uint4*)(const void*)(s + 16);
        d3 = *(const uint4*)(const void*)(s + 24);
      }
      ushort* dst = &ldsB[sp * 5120 + sr * 40];
      *(uint4*)(void*)dst = d0; *(uint4*)(void*)(dst + 8) = d1;
      *(uint4*)(void*)(dst + 16) = d2; *(uint4*)(void*)(dst + 24) = d3;
    }
    __syncthreads();
    bf16x8 af[2][4], bf[2][4];
#pragma unroll
    for (int p = 0; p < 2; p++)
#pragma unroll
      for (int mi = 0; mi < 4; mi++)
        af[p][mi] = *(const bf16x8*)&ldsA[p * 5120 + (wm + mi * 16 + lrow) * 40 + kq * 8];
#pragma unroll
    for (int p = 0; p < 2; p++)
#pragma unroll
      for (int ni = 0; ni < 4; ni++)
        bf[p][ni] = *(const bf16x8*)&ldsB[p * 5120 + (wn + ni * 16 + lrow) * 40 + kq * 8];
#pragma unroll
    for (int mi = 0; mi < 4; mi++)
#pragma unroll
      for (int ni = 0; ni < 4; ni++)
        acc[mi][ni] = __builtin_amdgcn_mfma_f32_16x16x32_bf16(
            af[0][mi], bf[0][ni], acc[mi][ni], 0, 0, 0);
#pragma unroll
    for (int mi = 0; mi < 4; mi++)
#pragma unroll
      for (int ni = 0; ni < 4; ni++)
        acc[mi][ni] = __builtin_amdgcn_mfma_f32_16x16x32_bf16(
            af[0][mi], bf[1][ni], acc[mi][ni], 0, 0, 0);
#pragma unroll
    for (int mi = 0; mi < 4; mi++)
#pragma unroll
      for (int ni = 0; ni < 4; ni++)
        acc[mi][ni] = __builtin_amdgcn_mfma_f32_16x16x32_bf16(
            af[1][mi], bf[0][ni], acc[mi][ni], 0, 0, 0);
  }

#pragma unroll
  for (int mi = 0; mi < 4; mi++) {
#pragma unroll
    for (int r = 0; r < 4; r++) {
      int i = i0 + wm + mi * 16 + kq * 4 + r;
      if (i >= M) continue;
#pragma unroll
      for (int ni = 0; ni < 4; ni++) {
        int j = j0 + wn + ni * 16 + lrow;
        if (j >= N) continue;
        float v = acc[mi][ni][r];
        if (MODE == 0) {
          if (bias) v += bias[j];
          of[(size_t)i * ldo + j] = v;
        } else if (MODE == 1) {
          size_t oi = (size_t)i * 768 + j;
          of[oi] = v + bias[j] + res[oi];
        } else if (MODE == 2) {
          v *= scale;
          ushort h, l;
          split_bf16(v, h, l);
          size_t oi = (size_t)i * 768 + j;
          oh[oi] = h; ol[oi] = l;
        } else {
          int nn = i / mapL; int ll = i - nn * mapL;
          size_t oi = ((size_t)(nn * 1034 + mapOff + ll)) * 768 + j;
          v += bias[j];
          if (res) v += res[oi];
          of[oi] = v;
          if (oh) {
            ushort h, l;
            split_bf16(v, h, l);
            oh[oi] = h; ol[oi] = l;
          }
        }
      }
    }
  }
}

// ---------------- weight prep: W[o][c*9+dt] fp32 -> [dt][o][c] bf16 hi/lo --
__global__ void wprep_kernel(const float* __restrict__ W, ushort* __restrict__ wh,
                             ushort* __restrict__ wl, int J, int Cin) {
  size_t idx = (size_t)blockIdx.x * 256 + threadIdx.x;
  size_t tot = (size_t)9 * J * Cin;
  if (idx >= tot) return;
  int c = (int)(idx % Cin);
  size_t t2 = idx / Cin;
  int o = (int)(t2 % J);
  int dt = (int)(t2 / J);
  float f = W[(size_t)o * Cin * 9 + (size_t)c * 9 + dt];
  ushort h, l;
  split_bf16(f, h, l);
  wh[idx] = h; wl[idx] = l;
}

// ---------------- ln3 + split into padded bf16 planes ----------------------
__global__ __launch_bounds__(256) void ln_split_kernel(
    const float* __restrict__ in, const float* __restrict__ g,
    const float* __restrict__ b, ushort* __restrict__ oh, ushort* __restrict__ ol) {
  int row = blockIdx.x, tid = threadIdx.x;
  int n = row / 834, t = row - n * 834;
  const float* xp = in + (size_t)row * 768;
  float v0 = xp[tid], v1 = xp[tid + 256], v2 = xp[tid + 512];
  float s = v0 + v1 + v2;
  float sq = v0 * v0 + v1 * v1 + v2 * v2;
  __shared__ float red[8];
#pragma unroll
  for (int off = 32; off >= 1; off >>= 1) {
    s += __shfl_down(s, off, 64); sq += __shfl_down(sq, off, 64);
  }
  if ((tid & 63) == 0) { red[tid >> 6] = s; red[4 + (tid >> 6)] = sq; }
  __syncthreads();
  s = red[0] + red[1] + red[2] + red[3];
  sq = red[4] + red[5] + red[6] + red[7];
  float m = s * (1.f / 768.f);
  float var = sq * (1.f / 768.f) - m * m;
  float rs = rsqrtf(var + 1e-5f);
  size_t dbase = ((size_t)(n * 842 + 4 + t)) * 768;
  ushort h, l;
  float y0 = (v0 - m) * rs * g[tid] + b[tid];
  split_bf16(y0, h, l); oh[dbase + tid] = h; ol[dbase + tid] = l;
  float y1 = (v1 - m) * rs * g[tid + 256] + b[tid + 256];
  split_bf16(y1, h, l); oh[dbase + tid + 256] = h; ol[dbase + tid + 256] = l;
  float y2 = (v2 - m) * rs * g[tid + 512] + b[tid + 512];
  split_bf16(y2, h, l); oh[dbase + tid + 512] = h; ol[dbase + tid + 512] = l;
}

// ---------------- zero pad rows of zs (8 samples) and fmid (4 slots) -------
__global__ void pad_zero_kernel(ushort* __restrict__ zh, ushort* __restrict__ zl,
                                ushort* __restrict__ fh, ushort* __restrict__ fl) {
  int idx = blockIdx.x * 256 + threadIdx.x;
  if (idx < 49152) {
    int c = idx % 768; int t2 = idx / 768;
    int rr = t2 & 7; int n = t2 >> 3;
    int row = (rr < 4) ? rr : (834 + rr);
    size_t d = ((size_t)(n * 842 + row)) * 768 + c;
    zh[d] = 0; zl[d] = 0;
  } else {
    int k = idx - 49152;
    if (k >= 98304) return;
    int c = k % 3072; int t2 = k / 3072;
    int rr = t2 & 7; int sl = t2 >> 3;
    int row = (rr < 4) ? rr : (834 + rr);
    size_t d = ((size_t)(sl * 842 + row)) * 3072 + c;
    fh[d] = 0; fl[d] = 0;
  }
}

// ---------------- conv1d-as-9-shifted-GEMMs, split-bf16 MFMA (unchanged) ---
template <int BN, int WM, int WN, int MODE>
__global__ __launch_bounds__(256) void conv_mfma(
    const ushort* __restrict__ Ah, const ushort* __restrict__ Al,
    const ushort* __restrict__ Wh, const ushort* __restrict__ Wl,
    int Cin, int J, int n0,
    const float* __restrict__ bias,
    ushort* __restrict__ oh, ushort* __restrict__ ol,
    float* __restrict__ of, const float* __restrict__ res) {
  const int MI = WM / 16, NI = WN / 16;
  __shared__ ushort ldsA[2 * 136 * 40];
  __shared__ ushort ldsB[2 * BN * 40];
  const int tid = threadIdx.x;
  const int wave = tid >> 6, lane = tid & 63;
  const int lrow = lane & 15, kq = lane >> 4;
  const int t0 = blockIdx.x * 128;
  const int j0 = blockIdx.y * BN;
  const int bz = blockIdx.z;
  const int n_real = n0 + bz;
  const int an = (MODE == 1) ? n_real : bz;
  const int wm = (wave & 1) * WM;
  const int wn = (wave >> 1) * WN;

  f32x4 acc[MI][NI];
#pragma unroll
  for (int mi = 0; mi < MI; mi++)
#pragma unroll
    for (int ni = 0; ni < NI; ni++) acc[mi][ni] = (f32x4)0.f;

  for (int c0 = 0; c0 < Cin; c0 += 32) {
    __syncthreads();
    for (int task = tid; task < 544; task += 256) {
      int plane = task >= 272;
      int rem = task - plane * 272;
      int r = rem >> 1, h = rem & 1;
      const ushort* src = (plane ? Al : Ah) +
          ((size_t)(an * 842 + t0 + r)) * Cin + c0 + h * 16;
      uint4 d0 = *(const uint4*)(const void*)src;
      uint4 d1 = *(const uint4*)(const void*)(src + 8);
      ushort* dst = &ldsA[plane * 5440 + r * 40 + h * 16];
      *(uint4*)(void*)dst = d0;
      *(uint4*)(void*)(dst + 8) = d1;
    }
    for (int dt = 0; dt < 9; dt++) {
      if (dt > 0) __syncthreads();
      for (int task = tid; task < 4 * BN; task += 256) {
        int plane = task >= 2 * BN;
        int rem = task - plane * 2 * BN;
        int o = rem >> 1, h = rem & 1;
        const ushort* src = (plane ? Wl : Wh) +
            ((size_t)(dt * J + j0 + o)) * Cin + c0 + h * 16;
        uint4 d0 = *(const uint4*)(const void*)src;
        uint4 d1 = *(const uint4*)(const void*)(src + 8);
        ushort* dst = &ldsB[plane * (BN * 40) + o * 40 + h * 16];
        *(uint4*)(void*)dst = d0;
        *(uint4*)(void*)(dst + 8) = d1;
      }
      __syncthreads();
      bf16x8 af[2][MI], bf[2][NI];
#pragma unroll
      for (int p = 0; p < 2; p++)
#pragma unroll
        for (int mi = 0; mi < MI; mi++)
          af[p][mi] = *(const bf16x8*)&ldsA[p * 5440 +
              (dt + wm + mi * 16 + lrow) * 40 + kq * 8];
#pragma unroll
      for (int p = 0; p < 2; p++)
#pragma unroll
        for (int ni = 0; ni < NI; ni++)
          bf[p][ni] = *(const bf16x8*)&ldsB[p * (BN * 40) +
              (wn + ni * 16 + lrow) * 40 + kq * 8];
#pragma unroll
      for (int mi = 0; mi < MI; mi++)
#pragma unroll
        for (int ni = 0; ni < NI; ni++)
          acc[mi][ni] = __builtin_amdgcn_mfma_f32_16x16x32_bf16(
              af[0][mi], bf[0][ni], acc[mi][ni], 0, 0, 0);
#pragma unroll
      for (int mi = 0; mi < MI; mi++)
#pragma unroll
        for (int ni = 0; ni < NI; ni++)
          acc[mi][ni] = __builtin_amdgcn_mfma_f32_16x16x32_bf16(
              af[0][mi], bf[1][ni], acc[mi][ni], 0, 0, 0);
#pragma unroll
      for (int mi = 0; mi < MI; mi++)
#pragma unroll
        for (int ni = 0; ni < NI; ni++)
          acc[mi][ni] = __builtin_amdgcn_mfma_f32_16x16x32_bf16(
              af[1][mi], bf[0][ni], acc[mi][ni], 0, 0, 0);
    }
  }

#pragma unroll
  for (int ni = 0; ni < NI; ni++) {
    int o = j0 + wn + ni * 16 + lrow;
    float bo = bias[o];
#pragma unroll
    for (int mi = 0; mi < MI; mi++) {
#pragma unroll
      for (int r = 0; r < 4; r++) {
        int t = t0 + wm + mi * 16 + kq * 4 + r;
        if (t < 834) {
          float v = acc[mi][ni][r] + bo;
          if (MODE == 1) {
            v = gelu_exact(v);
            ushort h, l;
            split_bf16(v, h, l);
            size_t d = ((size_t)(bz * 842 + 4 + t)) * 3072 + o;
            oh[d] = h; ol[d] = l;
          } else {
            size_t d = ((size_t)(n_real * 834 + t)) * 768 + o;
            of[d] = v + res[d];
          }
        }
      }
    }
  }
}

// ---------------- cls/pos add ----------------------------------------------
__global__ void addpos_kernel(float* __restrict__ seq, const float* __restrict__ pos,
                              const float* __restrict__ cls) {
  int idx = blockIdx.x * 256 + threadIdx.x;
  if (idx >= 8 * 834 * 768) return;
  int c = idx % 768;
  int t = (idx / 768) % 834;
  int n = idx / (768 * 834);
  size_t off = ((size_t)(n * 1034 + t)) * 768 + c;
  float v = (t == 0) ? cls[c] : seq[off];
  seq[off] = v + pos[(size_t)t * 768 + c];
}

// ---------------- GroupNorm -> split planes --------------------------------
__global__ __launch_bounds__(256) void groupnorm_split(
    const float* __restrict__ seq, const float* __restrict__ g,
    const float* __restrict__ b, ushort* __restrict__ oh, ushort* __restrict__ ol) {
  int blk = blockIdx.x;
  int n = blk >> 5, grp = blk & 31;
  int tid = threadIdx.x;
  float s = 0.f, sq = 0.f;
  for (int e = tid; e < 20016; e += 256) {
    int t = e / 24; int cc = e - t * 24;
    float v = seq[((size_t)(n * 1034 + t)) * 768 + grp * 24 + cc];
    s += v; sq += v * v;
  }
  __shared__ float red[8];
#pragma unroll
  for (int off = 32; off >= 1; off >>= 1) {
    s += __shfl_down(s, off, 64); sq += __shfl_down(sq, off, 64);
  }
  if ((tid & 63) == 0) { red[tid >> 6] = s; red[4 + (tid >> 6)] = sq; }
  __syncthreads();
  s = red[0] + red[1] + red[2] + red[3];
  sq = red[4] + red[5] + red[6] + red[7];
  float m = s * (1.f / 20016.f);
  float var = sq * (1.f / 20016.f) - m * m;
  float rs = rsqrtf(var + 1e-6f);
  for (int e = tid; e < 20016; e += 256) {
    int t = e / 24; int cc = e - t * 24;
    int c = grp * 24 + cc;
    float v = seq[((size_t)(n * 1034 + t)) * 768 + c];
    float y = (v - m) * rs * g[c] + b[c];
    ushort h, l;
    split_bf16(y, h, l);
    size_t d = ((size_t)(n * 834 + t)) * 768 + c;
    oh[d] = h; ol[d] = l;
  }
}

// ---------------- LayerNorm per row -> split planes ------------------------
__global__ __launch_bounds__(256) void ln_rows_split(
    const float* __restrict__ in, const float* __restrict__ g,
    const float* __restrict__ b, ushort* __restrict__ oh, ushort* __restrict__ ol) {
  int row = blockIdx.x, tid = threadIdx.x;
  const float* xp = in + (size_t)row * 768;
  float v0 = xp[tid], v1 = xp[tid + 256], v2 = xp[tid + 512];
  float s = v0 + v1 + v2;
  float sq = v0 * v0 + v1 * v1 + v2 * v2;
  __shared__ float red[8];
#pragma unroll
  for (int off = 32; off >= 1; off >>= 1) {
    s += __shfl_down(s, off, 64); sq += __shfl_down(sq, off, 64);
  }
  if ((tid & 63) == 0) { red[tid >> 6] = s; red[4 + (tid >> 6)] = sq; }
  __syncthreads();
  s = red[0] + red[1] + red[2] + red[3];
  sq = red[4] + red[5] + red[6] + red[7];
  float m = s * (1.f / 768.f);
  float var = sq * (1.f / 768.f) - m * m;
  float rs = rsqrtf(var + 1e-5f);
  size_t dbase = (size_t)row * 768;
  ushort h, l;
  float y0 = (v0 - m) * rs * g[tid] + b[tid];
  split_bf16(y0, h, l); oh[dbase + tid] = h; ol[dbase + tid] = l;
  float y1 = (v1 - m) * rs * g[tid + 256] + b[tid + 256];
  split_bf16(y1, h, l); oh[dbase + tid + 256] = h; ol[dbase + tid + 256] = l;
  float y2 = (v2 - m) * rs * g[tid + 512] + b[tid + 512];
  split_bf16(y2, h, l); oh[dbase + tid + 512] = h; ol[dbase + tid + 512] = l;
}

// ---------------- MFMA flash attention -------------------------------------
// 64 q-rows/block, 4 waves (16 q-rows each), KV-tile 64, D=48.
// QK^T: 3-pass split (Q pre-scaled). P: hi-only. PV: Ph*Vh + Ph*Vl.
__global__ __launch_bounds__(256) void attn_mfma(
    const ushort* __restrict__ Qh, const ushort* __restrict__ Ql,
    const ushort* __restrict__ Kh, const ushort* __restrict__ Kl,
    const ushort* __restrict__ Vh, const ushort* __restrict__ Vl,
    ushort* __restrict__ Oh, ushort* __restrict__ Ol) {
  const int S = 834;
  __shared__ ushort sm[29952];
  ushort* Qs = sm;           // 2 planes x 64 x 72
  ushort* Ks = sm + 9216;    // 2 planes x 64 x 72
  ushort* Vt = sm + 18432;   // 2 planes x 48 x 72 (transposed: [d][kv])
  ushort* Ps = sm + 25344;   // 1 plane  x 64 x 72
  const int tid = threadIdx.x;
  const int wave = tid >> 6, lane = tid & 63;
  const int lrow = lane & 15, kq = lane >> 4;
  const int qt = blockIdx.x, head = blockIdx.y, n = blockIdx.z;
  const size_t base = ((size_t)n * S) * 768 + head * 48;

  for (int e = tid; e < 18432; e += 256) sm[e] = 0;
  __syncthreads();
  if (tid < 128) {
    int r = tid >> 1, p = tid & 1;
    int q = qt * 64 + r;
    if (q < S) {
      const ushort* s = (p ? Ql : Qh) + base + (size_t)q * 768;
      ushort* d = &Qs[p * 4608 + r * 72];
#pragma unroll
      for (int seg = 0; seg < 6; seg++)
        *(uint4*)(void*)(d + seg * 8) = *(const uint4*)(const void*)(s + seg * 8);
    }
  }
  __syncthreads();

  bf16x8 aq[2][2];
#pragma unroll
  for (int p = 0; p < 2; p++)
#pragma unroll
    for (int c = 0; c < 2; c++)
      aq[p][c] = *(const bf16x8*)&Qs[p * 4608 + (wave * 16 + lrow) * 72 + c * 32 + kq * 8];

  float m4[4], l4[4];
  f32x4 accO[3];
#pragma unroll
  for (int r = 0; r < 4; r++) { m4[r] = -1e30f; l4[r] = 0.f; }
#pragma unroll
  for (int d = 0; d < 3; d++) accO[d] = (f32x4)0.f;

  for (int kt = 0; kt < S; kt += 64) {
    __syncthreads();
    if (tid < 128) {
      int r = tid >> 1, p = tid & 1;
      int ki = kt + r;
      if (ki < S) {
        const ushort* s = (p ? Kl : Kh) + base + (size_t)ki * 768;
        ushort* d = &Ks[p * 4608 + r * 72];
#pragma unroll
        for (int seg = 0; seg < 6; seg++)
          *(uint4*)(void*)(d + seg * 8) = *(const uint4*)(const void*)(s + seg * 8);
      }
    }
    for (int e = tid; e < 768; e += 256) {
      int p = e >= 384;
      int rem = e - p * 384;
      int kv = rem / 6, seg = rem - kv * 6;
      if (kt + kv < S) {
        uint4 d = *(const uint4*)(const void*)((p ? Vl : Vh) + base +
                                               (size_t)(kt + kv) * 768 + seg * 8);
        ushort* dst = &Vt[p * 3456 + kv];
        uint w[4] = {d.x, d.y, d.z, d.w};
#pragma unroll
        for (int u = 0; u < 4; u++) {
          dst[(seg * 8 + u * 2 + 0) * 72] = (ushort)(w[u] & 0xFFFFu);
          dst[(seg * 8 + u * 2 + 1) * 72] = (ushort)(w[u] >> 16);
        }
      }
    }
    __syncthreads();

    // QK^T
    f32x4 s4[4];
#pragma unroll
    for (int ni = 0; ni < 4; ni++) s4[ni] = (f32x4)0.f;
#pragma unroll
    for (int ni = 0; ni < 4; ni++) {
      bf16x8 bk[2][2];
#pragma unroll
      for (int p = 0; p < 2; p++)
#pragma unroll
        for (int c = 0; c < 2; c++)
          bk[p][c] = *(const bf16x8*)&Ks[p * 4608 + (ni * 16 + lrow) * 72 + c * 32 + kq * 8];
#pragma unroll
      for (int c = 0; c < 2; c++)
        s4[ni] = __builtin_amdgcn_mfma_f32_16x16x32_bf16(aq[0][c], bk[0][c], s4[ni], 0, 0, 0);
#pragma unroll
      for (int c = 0; c < 2; c++)
        s4[ni] = __builtin_amdgcn_mfma_f32_16x16x32_bf16(aq[0][c], bk[1][c], s4[ni], 0, 0, 0);
#pragma unroll
      for (int c = 0; c < 2; c++)
        s4[ni] = __builtin_amdgcn_mfma_f32_16x16x32_bf16(aq[1][c], bk[0][c], s4[ni], 0, 0, 0);
    }

    // online softmax (lane rows: kq*4 + r)
    bool valid[4];
#pragma unroll
    for (int ni = 0; ni < 4; ni++) valid[ni] = (kt + ni * 16 + lrow) < S;
    float pv[4][4];
#pragma unroll
    for (int r = 0; r < 4; r++) {
      float sv[4], mx = -1e30f;
#pragma unroll
      for (int ni = 0; ni < 4; ni++) {
        sv[ni] = valid[ni] ? s4[ni][r] : -1e30f;
        mx = fmaxf(mx, sv[ni]);
      }
#pragma unroll
      for (int off = 8; off >= 1; off >>= 1) mx = fmaxf(mx, __shfl_xor(mx, off, 64));
      float mnew = fmaxf(m4[r], mx);
      float al = __expf(m4[r] - mnew);
      float ps = 0.f;
#pragma unroll
      for (int ni = 0; ni < 4; ni++) {
        float p = valid[ni] ? __expf(sv[ni] - mnew) : 0.f;
        pv[ni][r] = p; ps += p;
      }
#pragma unroll
      for (int off = 8; off >= 1; off >>= 1) ps += __shfl_xor(ps, off, 64);
      l4[r] = l4[r] * al + ps;
      m4[r] = mnew;
#pragma unroll
      for (int d = 0; d < 3; d++) accO[d][r] *= al;
    }
    // write P (hi only), wave-local region
#pragma unroll
    for (int ni = 0; ni < 4; ni++)
#pragma unroll
      for (int r = 0; r < 4; r++)
        Ps[(wave * 16 + kq * 4 + r) * 72 + ni * 16 + lrow] = bf16_rnd(pv[ni][r]);

    // PV
    bf16x8 ap[2];
#pragma unroll
    for (int c = 0; c < 2; c++)
      ap[c] = *(const bf16x8*)&Ps[(wave * 16 + lrow) * 72 + c * 32 + kq * 8];
#pragma unroll
    for (int d = 0; d < 3; d++) {
      bf16x8 bv[2][2];
#pragma unroll
      for (int p = 0; p < 2; p++)
#pragma unroll
        for (int c = 0; c < 2; c++)
          bv[p][c] = *(const bf16x8*)&Vt[p * 3456 + (d * 16 + lrow) * 72 + c * 32 + kq * 8];
#pragma unroll
      for (int c = 0; c < 2; c++)
        accO[d] = __builtin_amdgcn_mfma_f32_16x16x32_bf16(ap[c], bv[0][c], accO[d], 0, 0, 0);
#pragma unroll
      for (int c = 0; c < 2; c++)
        accO[d] = __builtin_amdgcn_mfma_f32_16x16x32_bf16(ap[c], bv[1][c], accO[d], 0, 0, 0);
    }
  }

#pragma unroll
  for (int r = 0; r < 4; r++) {
    int q = qt * 64 + wave * 16 + kq * 4 + r;
    if (q >= S) continue;
    float inv = 1.f / l4[r];
#pragma unroll
    for (int d = 0; d < 3; d++) {
      float v = accO[d][r] * inv;
      ushort h, l;
      split_bf16(v, h, l);
      size_t oi = base + (size_t)q * 768 + d * 16 + lrow;
      Oh[oi] = h; Ol[oi] = l;
    }
  }
}

// ---------------- GRU (torch cell) + masked-mean head ----------------------
__global__ __launch_bounds__(64) void gru_kernel(
    const float* __restrict__ gx, const float* __restrict__ whh,
    const float* __restrict__ bhh, const float* __restrict__ qh_w,
    const float* __restrict__ qh_b, const int* __restrict__ fea_len,
    float* __restrict__ out) {
  int n = blockIdx.x;
  int lane = threadIdx.x;
  bool lo = lane < 32;
  float w1[32], w2[32];
#pragma unroll
  for (int i = 0; i < 32; i++) w1[i] = whh[lane * 32 + i];
#pragma unroll
  for (int i = 0; i < 32; i++) w2[i] = lo ? whh[(64 + lane) * 32 + i] : 0.f;
  float bh1 = bhh[lane];
  float bh2 = lo ? bhh[64 + lane] : 0.f;
  float qw  = lo ? qh_w[lane] : 0.f;
  float h_all[32];
#pragma unroll
  for (int i = 0; i < 32; i++) h_all[i] = 0.f;
  float hown = 0.f, acc = 0.f;
  int L = fea_len[n] + 834;
  const float* gb = gx + (size_t)n * 1034 * 96;
  for (int t = 0; t < 1034; t++) {
    if (t >= L) break;
    const float* g = gb + (size_t)t * 96;
    float g1 = g[lane];
    float g2 = lo ? g[64 + lane] : 0.f;
    float gh1 = bh1, gh2 = bh2;
#pragma unroll
    for (int i = 0; i < 32; i++) {
      gh1 = fmaf(h_all[i], w1[i], gh1);
      gh2 = fmaf(h_all[i], w2[i], gh2);
    }
    float s1 = g1 + gh1;
    float szg = __shfl(s1, (lane + 32) & 63, 64);
    float rg = 1.f / (1.f + expf(-s1));
    float zg = 1.f / (1.f + expf(-szg));
    float nn = tanhf(fmaf(rg, gh2, g2));
    float hn = (1.f - zg) * nn + zg * hown;
    if (lo) { hown = hn; acc = fmaf(hn, qw, acc); }
#pragma unroll
    for (int i = 0; i < 32; i++) h_all[i] = __shfl(hn, i, 64);
  }
#pragma unroll
  for (int off = 16; off >= 1; off >>= 1) acc += __shfl_down(acc, off, 64);
  if (lane == 0) out[n] = acc / (float)L + qh_b[0];
}

// ---------------------------------------------------------------------------
extern "C" void kernel_launch(void* const* d_in, const int* in_sizes, int n_in,
                              void* d_out, int out_size, void* d_ws, size_t ws_size,
                              hipStream_t stream) {
  const float* x        = (const float*)d_in[0];
  const float* spa_feas = (const float*)d_in[1];
  const int*   fea_len  = (const int*)d_in[2];
  const float* pos_emb  = (const float*)d_in[3];
  const float* cls_tok  = (const float*)d_in[4];
  const float* conv_w   = (const float*)d_in[5];
  const float* conv_b   = (const float*)d_in[6];
  const float* gn_g     = (const float*)d_in[7];
  const float* gn_b     = (const float*)d_in[8];
  const float* pin_w    = (const float*)d_in[9];
  const float* pin_b    = (const float*)d_in[10];
  const float* ln_g[3]  = {(const float*)d_in[11], (const float*)d_in[13], (const float*)d_in[15]};
  const float* ln_b[3]  = {(const float*)d_in[12], (const float*)d_in[14], (const float*)d_in[16]};
  const float* wq[2] = {(const float*)d_in[17], (const float*)d_in[22]};
  const float* wk[2] = {(const float*)d_in[18], (const float*)d_in[23]};
  const float* wv[2] = {(const float*)d_in[19], (const float*)d_in[24]};
  const float* wo[2] = {(const float*)d_in[20], (const float*)d_in[25]};
  const float* bo[2] = {(const float*)d_in[21], (const float*)d_in[26]};
  const float* ff_w1 = (const float*)d_in[27];
  const float* ff_b1 = (const float*)d_in[28];
  const float* ff_w2 = (const float*)d_in[29];
  const float* ff_b2 = (const float*)d_in[30];
  const float* pout_w = (const float*)d_in[31];
  const float* pout_b = (const float*)d_in[32];
  const float* spa_w  = (const float*)d_in[33];
  const float* spa_b  = (const float*)d_in[34];
  const float* gru_wih = (const float*)d_in[35];
  const float* gru_whh = (const float*)d_in[36];
  const float* gru_bih = (const float*)d_in[37];
  const float* gru_bhh = (const float*)d_in[38];
  const float* qh_w = (const float*)d_in[39];
  const float* qh_b = (const float*)d_in[40];
  float* outp = (float*)d_out;

  // ---- workspace: fp32 seq + z, then ushort arena R (same 203 MiB total) --
  float* ws  = (float*)d_ws;
  float* seq = ws;                 // 6,352,896 fl
  float* z   = seq + 6352896;      // 5,124,096 fl
  ushort* R  = (ushort*)(ws + 11476992);  // 83,573,760 ushorts

  // encoder-phase cursor layout
  size_t co = 0;
  ushort* pinH = R + co; co += 589824; ushort* pinL = R + co; co += 589824;
  ushort *wqH[2], *wqL[2], *wkH[2], *wkL[2], *wvH[2], *wvL[2], *woH[2], *woL[2];
  for (int l = 0; l < 2; l++) {
    wqH[l] = R + co; co += 589824; wqL[l] = R + co; co += 589824;
    wkH[l] = R + co; co += 589824; wkL[l] = R + co; co += 589824;
    wvH[l] = R + co; co += 589824; wvL[l] = R + co; co += 589824;
    woH[l] = R + co; co += 589824; woL[l] = R + co; co += 589824;
  }
  ushort* aPh = R + co; co += 5124096; ushort* aPl = R + co; co += 5124096;
  ushort* QPh = R + co; co += 5124096; ushort* QPl = R + co; co += 5124096;
  ushort* KPh = R + co; co += 5124096; ushort* KPl = R + co; co += 5124096;
  ushort* VPh = R + co; co += 5124096; ushort* VPl = R + co; co += 5124096;
  ushort* oPh = R + co; co += 5124096; ushort* oPl = R + co; co += 5124096;
  // tokenize tail scratch
  ushort* colH = R + co; co += 2709504; ushort* colL = R + co; co += 2709504;
  ushort* cwH  = R + co; co += 1179648; ushort* cwL  = R + co; co += 1179648;
  ushort* w1rH = R + co; co += 589824;  ushort* w1rL = R + co; co += 589824;
  ushort* w2rH = R + co; co += 1327104; ushort* w2rL = R + co; co += 1327104;
  // (co ~= 73.5M <= 83,573,760)

  // FFN-phase fixed offsets (overlap encoder regions, all dead by then)
  ushort* zsH = R;                ushort* zsL = R + 5223936;
  ushort* fmH = R + 10447872;     ushort* fmL = R + 20997120;
  ushort* ffwH = R + 40992768;    ushort* ffwL = R + 62226432;
  // post-FFN fixed offsets (overlap ffW region, dead after conv2)
  ushort* zPh = R + 40992768;     ushort* zPl = R + 46116864;
  ushort* poutH = R + 51240960;   ushort* poutL = R + 51830784;
  ushort* spaWH = R + 52420608;   ushort* spaWL = R + 53993472;
  ushort* wihH = R + 55566336;    ushort* wihL = R + 55640064;
  ushort* spaInH = R + 55713792;  ushort* spaInL = R + 58990592;
  ushort* seqPh = R;              ushort* seqPl = R + 6352896;
  float* gx = (float*)(R + 12705792);

  const float QSCALE = 0.14433756729740644f;  // 48^-0.5

  // ---- tokenize ----
  resize_w_split<<<2304, 256, 0, stream>>>(conv_w, w1rH, w1rL, 16, 4, 4);
  resize_w_split<<<5184, 256, 0, stream>>>(conv_w, w2rH, w2rL, 4, 12, 12);
  wsplit_kernel<<<1152, 256, 0, stream>>>(conv_w, cwH, cwL, 294912);
  im2col_split<<<9408, 256, 0, stream>>>(x, colH, colL, 1568, 1536, 196, 8, 8, 8, 16, 32, 32);
  gemm_bf3<3><<<dim3(6, 13), 256, 0, stream>>>(colH, colL, cwH, cwL, 1568, 768, 1536,
      conv_b, nullptr, 1.f, seq, nullptr, nullptr, 196, 1, 768);
  im2col_split<<<10584, 256, 0, stream>>>(x, colH, colL, 3528, 768, 441, 16, 4, 4, 6, 32, 32);
  gemm_bf3<3><<<dim3(6, 28), 256, 0, stream>>>(colH, colL, w1rH, w1rL, 3528, 768, 768,
      conv_b + 768, nullptr, 1.f, seq, nullptr, nullptr, 441, 197, 768);
  im2col_split<<<10584, 256, 0, stream>>>(x, colH, colL, 1568, 1728, 196, 4, 12, 12, 16, 32, 32);
  gemm_bf3<3><<<dim3(6, 13), 256, 0, stream>>>(colH, colL, w2rH, w2rL, 1568, 768, 1728,
      conv_b + 1536, nullptr, 1.f, seq, nullptr, nullptr, 196, 638, 768);
  addpos_kernel<<<20016, 256, 0, stream>>>(seq, pos_emb, cls_tok);

  // ---- encoder weight splits ----
  wsplit_kernel<<<576, 256, 0, stream>>>(pin_w, pinH, pinL, 147456);
  for (int l = 0; l < 2; l++) {
    wsplit_kernel<<<576, 256, 0, stream>>>(wq[l], wqH[l], wqL[l], 147456);
    wsplit_kernel<<<576, 256, 0, stream>>>(wk[l], wkH[l], wkL[l], 147456);
    wsplit_kernel<<<576, 256, 0, stream>>>(wv[l], wvH[l], wvL[l], 147456);
    wsplit_kernel<<<576, 256, 0, stream>>>(wo[l], woH[l], woL[l], 147456);
  }

  // ---- temporal encoder ----
  groupnorm_split<<<256, 256, 0, stream>>>(seq, gn_g, gn_b, aPh, aPl);
  gemm_bf3<0><<<dim3(6, 53), 256, 0, stream>>>(aPh, aPl, pinH, pinL, 6672, 768, 768,
      pin_b, nullptr, 1.f, z, nullptr, nullptr, 0, 0, 768);

  for (int l = 0; l < 2; l++) {
    ln_rows_split<<<6672, 256, 0, stream>>>(z, ln_g[l], ln_b[l], aPh, aPl);
    gemm_bf3<2><<<dim3(6, 53), 256, 0, stream>>>(aPh, aPl, wqH[l], wqL[l], 6672, 768, 768,
        nullptr, nullptr, QSCALE, nullptr, QPh, QPl, 0, 0, 768);
    gemm_bf3<2><<<dim3(6, 53), 256, 0, stream>>>(aPh, aPl, wkH[l], wkL[l], 6672, 768, 768,
        nullptr, nullptr, 1.f, nullptr, KPh, KPl, 0, 0, 768);
    gemm_bf3<2><<<dim3(6, 53), 256, 0, stream>>>(aPh, aPl, wvH[l], wvL[l], 6672, 768, 768,
        nullptr, nullptr, 1.f, nullptr, VPh, VPl, 0, 0, 768);
    attn_mfma<<<dim3(14, 16, 8), 256, 0, stream>>>(QPh, QPl, KPh, KPl, VPh, VPl, oPh, oPl);
    gemm_bf3<1><<<dim3(6, 53), 256, 0, stream>>>(oPh, oPl, woH[l], woL[l], 6672, 768, 768,
        bo[l], z, 1.f, z, nullptr, nullptr, 0, 0, 768);
  }

  // ---- FFN (conv1d k=9) via split-bf16 MFMA, two n-halves ----
  ln_split_kernel<<<6672, 256, 0, stream>>>(z, ln_g[2], ln_b[2], zsH, zsL);
  pad_zero_kernel<<<576, 256, 0, stream>>>(zsH, zsL, fmH, fmL);
  for (int half = 0; half < 2; half++) {
    int n0 = half * 4;
    wprep_kernel<<<82944, 256, 0, stream>>>(ff_w1, ffwH, ffwL, 3072, 768);
    conv_mfma<128, 64, 64, 1><<<dim3(7, 24, 4), 256, 0, stream>>>(
        zsH, zsL, ffwH, ffwL, 768, 3072, n0, ff_b1, fmH, fmL, nullptr, nullptr);
    wprep_kernel<<<82944, 256, 0, stream>>>(ff_w2, ffwH, ffwL, 768, 3072);
    conv_mfma<64, 64, 32, 2><<<dim3(7, 12, 4), 256, 0, stream>>>(
        fmH, fmL, ffwH, ffwL, 3072, 768, n0, ff_b2, nullptr, nullptr, z, z);
  }

  // ---- post: splits, pout + spa into seq (+planes), GRU ----
  wsplit_kernel<<<5005, 256, 0, stream>>>(z, zPh, zPl, 1281024);
  wsplit_kernel<<<576, 256, 0, stream>>>(pout_w, poutH, poutL, 147456);
  wsplit_kernel<<<1536, 256, 0, stream>>>(spa_w, spaWH, spaWL, 393216);
  wsplit_kernel<<<72, 256, 0, stream>>>(gru_wih, wihH, wihL, 18432);
  wsplit_kernel<<<3200, 256, 0, stream>>>(spa_feas, spaInH, spaInL, 819200);
  gemm_bf3<3><<<dim3(6, 53), 256, 0, stream>>>(zPh, zPl, poutH, poutL, 6672, 768, 768,
      pout_b, seq, 1.f, seq, seqPh, seqPl, 834, 0, 768);
  gemm_bf3<3><<<dim3(6, 13), 256, 0, stream>>>(spaInH, spaInL, spaWH, spaWL, 1600, 768, 2048,
      spa_b, nullptr, 1.f, seq, seqPh, seqPl, 200, 834, 768);
  gemm_bf3<0><<<dim3(1, 65), 256, 0, stream>>>(seqPh, seqPl, wihH, wihL, 8272, 96, 768,
      gru_bih, nullptr, 1.f, gx, nullptr, nullptr, 0, 0, 96);
  gru_kernel<<<8, 64, 0, stream>>>(gx, gru_whh, gru_bhh, qh_w, qh_b, fea_len, outp);
}